// Round 9
// baseline (1283.764 us; speedup 1.0000x reference)
//
#include <hip/hip_runtime.h>
#include <hip/hip_cooperative_groups.h>

namespace cg = cooperative_groups;

#define NN 100000
#define NE 1600000
#define HD 128
#define NG 128
#define NC 10
#define EPSV 1e-5f

#define BSH 9                      // 512 dst nodes per bucket
#define NBKT ((NN + 511) >> 9)     // 196
#define BIN_BLOCKS ((NE + 4095) / 4096)  // 391
#define STAT_CH 8
#define POOL_CH 16

typedef __attribute__((ext_vector_type(8))) short short8;
typedef __attribute__((ext_vector_type(4))) float f32x4;

__device__ __forceinline__ float b2f(ushort u){ return __uint_as_float(((unsigned)u)<<16); }
__device__ __forceinline__ ushort f2b(float f){
  unsigned u = __float_as_uint(f);
  unsigned r = (u + 0x7FFFu + ((u>>16)&1u)) >> 16;   // RNE
  return (ushort)r;
}

// ============================================================================================
// Shared phase bodies (device inline) used by BOTH cooperative and classic kernels
// ============================================================================================

__device__ __forceinline__ void init_body(int vb, int t, const int* batch, int* gstart,
    const float* w1, const float* w2, const float* w3, ushort* wT, int* gbhist, float* zero_base)
{
  if(vb < 391){                        // granges: batch sorted -> contiguous segments
    int n = vb*256 + t;
    if(n < NN){
      int bb = batch[n];
      if(n == 0){
        for(int g=0; g<=bb; g++) gstart[g] = 0;
        int last = batch[NN-1];
        for(int g=last+1; g<=NG; g++) gstart[g] = NN;
      } else {
        int bp = batch[n-1];
        for(int g=bp+1; g<=bb; g++) gstart[g] = n;
      }
    }
  } else if(vb < 394){                 // wT[layer][h][k] = bf16(w[k][h])
    const float* w = (vb == 391) ? w1 : (vb == 392) ? w2 : w3;
    ushort* o = wT + (vb-391)*16384;
    #pragma unroll 4
    for(int i=0;i<64;i++){
      int e = i*256 + t;
      o[(e & 127)*128 + (e >> 7)] = f2b(w[e]);
    }
  } else if(vb < 408){                 // zero 3x(S1,S2)+pooled = 114688 floats
    #pragma unroll 8
    for(int i=0;i<32;i++) zero_base[(size_t)(vb-394)*8192 + i*256 + t] = 0.f;
  } else {
    if(t < NBKT) gbhist[t] = 0;
  }
}

// ============================================================================================
// Classic kernels (round-7 known-good fallback path)
// ============================================================================================

__global__ __launch_bounds__(256)
void k_init(const int* __restrict__ batch, int* __restrict__ gstart,
            const float* __restrict__ w1, const float* __restrict__ w2,
            const float* __restrict__ w3, ushort* __restrict__ wT,
            int* __restrict__ gbhist, float* __restrict__ zero_base)
{
  init_body(blockIdx.x, threadIdx.x, batch, gstart, w1, w2, w3, wT, gbhist, zero_base);
}

__global__ __launch_bounds__(256) void k_bhist(const int* __restrict__ ei, int* __restrict__ gbhist){
  __shared__ int h[NBKT];
  int t = threadIdx.x;
  if(t < NBKT) h[t] = 0;
  __syncthreads();
  int base = blockIdx.x*4096;
  #pragma unroll
  for(int i=0;i<16;i++){
    int e = base + i*256 + t;
    if(e < NE) atomicAdd(&h[ei[NE + e] >> BSH], 1);
  }
  __syncthreads();
  if(t < NBKT && h[t]) atomicAdd(&gbhist[t], h[t]);
}

__global__ void k_bscan(const int* __restrict__ gbhist, int* __restrict__ bucket_base,
                        int* __restrict__ bucket_cursor, int* __restrict__ rowstart){
  __shared__ int lds[256];
  int t = threadIdx.x;
  int v = (t < NBKT) ? gbhist[t] : 0;
  lds[t] = v; __syncthreads();
  for(int off=1; off<256; off<<=1){
    int y = lds[t]; int z = (t>=off)?lds[t-off]:0;
    __syncthreads(); lds[t] = y+z; __syncthreads();
  }
  int excl = (t>0)?lds[t-1]:0;
  if(t < NBKT){ bucket_base[t] = excl; bucket_cursor[t] = excl; }
  if(t == 0){ bucket_base[NBKT] = NE; rowstart[NN] = NE; }
}

__global__ __launch_bounds__(256) void k_bin(const int* __restrict__ ei, int* __restrict__ bucket_cursor,
                                             unsigned* __restrict__ ebuf){
  __shared__ unsigned eb[4096];
  __shared__ unsigned char bb4[4096];
  __shared__ int hist[NBKT], lstart[NBKT], lcur[NBKT], rbase[NBKT];
  __shared__ int scanbuf[256];
  int t = threadIdx.x;
  if(t < NBKT) hist[t] = 0;
  __syncthreads();
  int base = blockIdx.x*4096;
  int nv = NE - base; if(nv > 4096) nv = 4096;
  int se[16], de[16];
  #pragma unroll
  for(int i=0;i<16;i++){
    int e = base + i*256 + t;
    if(e < NE){ se[i] = ei[e]; de[i] = ei[NE + e]; atomicAdd(&hist[de[i] >> BSH], 1); }
  }
  __syncthreads();
  int v = (t < NBKT) ? hist[t] : 0;
  scanbuf[t] = v; __syncthreads();
  for(int off=1; off<256; off<<=1){
    int y = scanbuf[t]; int z = (t>=off)?scanbuf[t-off]:0;
    __syncthreads(); scanbuf[t] = y+z; __syncthreads();
  }
  if(t < NBKT){
    int excl = (t>0)?scanbuf[t-1]:0;
    lstart[t] = excl; lcur[t] = excl;
    if(hist[t]) rbase[t] = atomicAdd(&bucket_cursor[t], hist[t]);
  }
  __syncthreads();
  #pragma unroll
  for(int i=0;i<16;i++){
    int e = base + i*256 + t;
    if(e < NE){
      int b = de[i] >> BSH;
      int idx = atomicAdd(&lcur[b], 1);
      eb[idx] = ((unsigned)(de[i] & 511) << 17) | (unsigned)se[i];
      bb4[idx] = (unsigned char)b;
    }
  }
  __syncthreads();
  #pragma unroll
  for(int i=0;i<16;i++){
    int slot = i*256 + t;
    if(slot < nv){
      int b = bb4[slot];
      ebuf[rbase[b] + (slot - lstart[b])] = eb[slot];
    }
  }
}

__global__ __launch_bounds__(256) void k_sort(const unsigned* __restrict__ ebuf,
                                              const int* __restrict__ bucket_base,
                                              int* __restrict__ srcs, int* __restrict__ rowstart,
                                              float* __restrict__ dinv){
  __shared__ int hist[512], cur[512];
  __shared__ int scanbuf[256];
  int b = blockIdx.x, t = threadIdx.x;
  int e0 = bucket_base[b], e1 = bucket_base[b+1];
  hist[t] = 0; hist[t+256] = 0;
  __syncthreads();
  for(int i = e0 + t; i < e1; i += 256)
    atomicAdd(&hist[ebuf[i] >> 17], 1);
  __syncthreads();
  int s0 = hist[2*t], s1 = hist[2*t+1];
  scanbuf[t] = s0 + s1; __syncthreads();
  for(int off=1; off<256; off<<=1){
    int y = scanbuf[t]; int z = (t>=off)?scanbuf[t-off]:0;
    __syncthreads(); scanbuf[t] = y+z; __syncthreads();
  }
  int excl = (t>0)?scanbuf[t-1]:0;
  cur[2*t] = excl; cur[2*t+1] = excl + s0;
  int d0 = (b << BSH) + 2*t, d1 = d0 + 1;
  if(d0 < NN){ rowstart[d0] = e0 + excl;      dinv[d0] = rsqrtf((float)(s0 + 1)); }
  if(d1 < NN){ rowstart[d1] = e0 + excl + s0; dinv[d1] = rsqrtf((float)(s1 + 1)); }
  __syncthreads();
  for(int i = e0 + t; i < e1; i += 256){
    unsigned pk = ebuf[i];
    int dl = pk >> 17;
    int pos = e0 + atomicAdd(&cur[dl], 1);
    srcs[pos] = (int)(pk & 0x1FFFFu);
  }
}

// classic MFMA GEMM (128-row tile)
template<int NORM>
__global__ __launch_bounds__(256)
void k_gemm(const void* __restrict__ in_, const ushort* __restrict__ wT,
            ushort* __restrict__ g, const float* __restrict__ dinv,
            const int* __restrict__ batch,
            const float* __restrict__ gw, const float* __restrict__ gb,
            const float* __restrict__ ga, const float* __restrict__ S1,
            const float* __restrict__ S2, const int* __restrict__ gstart)
{
  __shared__ ushort lds_a[128*136];
  __shared__ float sdinv[128];
  const int t = threadIdx.x;
  const int row0 = blockIdx.x * 128;
  {
    const int l = t & 31;
    const int rr = t >> 5;
    if(t < 128){
      int node = row0 + t;
      sdinv[t] = (node < NN) ? dinv[node] : 0.f;
    }
    float4 gwv, gbv, gav;
    float4 amv = make_float4(0.f,0.f,0.f,0.f), rsv = make_float4(0.f,0.f,0.f,0.f);
    int gprev = -1;
    if(NORM){
      gwv = ((const float4*)gw)[l]; gbv = ((const float4*)gb)[l];
      gav = ((const float4*)ga)[l];
    }
    #pragma unroll 4
    for(int rb = 0; rb < 16; rb++){
      int r = rb*8 + rr;
      int node = row0 + r;
      float4 v = make_float4(0.f,0.f,0.f,0.f);
      if(node < NN){
        if(NORM){
          ushort4 raw = ((const ushort4*)in_)[(size_t)node*32 + l];
          v = make_float4(b2f(raw.x), b2f(raw.y), b2f(raw.z), b2f(raw.w));
          int gg = batch[node];
          if(gg != gprev){
            gprev = gg;
            int c0 = gstart[gg], c1 = gstart[gg+1];
            float inv = 1.f/(float)((c1-c0) > 0 ? (c1-c0) : 1);
            float4 s1v = ((const float4*)S1)[gg*32 + l];
            float4 s2v = ((const float4*)S2)[gg*32 + l];
            float m, ex2, a;
            m = s1v.x*inv; ex2 = s2v.x*inv; a = gav.x;
            amv.x = a*m; rsv.x = rsqrtf(ex2 - (2.f*a - a*a)*m*m + EPSV);
            m = s1v.y*inv; ex2 = s2v.y*inv; a = gav.y;
            amv.y = a*m; rsv.y = rsqrtf(ex2 - (2.f*a - a*a)*m*m + EPSV);
            m = s1v.z*inv; ex2 = s2v.z*inv; a = gav.z;
            amv.z = a*m; rsv.z = rsqrtf(ex2 - (2.f*a - a*a)*m*m + EPSV);
            m = s1v.w*inv; ex2 = s2v.w*inv; a = gav.w;
            amv.w = a*m; rsv.w = rsqrtf(ex2 - (2.f*a - a*a)*m*m + EPSV);
          }
          v.x = fmaxf(gwv.x*(v.x-amv.x)*rsv.x + gbv.x, 0.f);
          v.y = fmaxf(gwv.y*(v.y-amv.y)*rsv.y + gbv.y, 0.f);
          v.z = fmaxf(gwv.z*(v.z-amv.z)*rsv.z + gbv.z, 0.f);
          v.w = fmaxf(gwv.w*(v.w-amv.w)*rsv.w + gbv.w, 0.f);
        } else {
          v = ((const float4*)in_)[(size_t)node*32 + l];
        }
      }
      ushort4 b4;
      b4.x = f2b(v.x); b4.y = f2b(v.y); b4.z = f2b(v.z); b4.w = f2b(v.w);
      *(ushort4*)(lds_a + r*136 + l*4) = b4;
    }
  }
  __syncthreads();

  const int wv = t >> 6, l = t & 63, lc = l & 15, lk = l >> 4;
  short8 bfrag[2][4];
  #pragma unroll
  for(int tt=0; tt<2; tt++){
    int col = wv*32 + tt*16 + lc;
    #pragma unroll
    for(int s=0; s<4; s++)
      bfrag[tt][s] = *(const short8*)(wT + col*128 + s*32 + lk*8);
  }
  f32x4 acc[8][2];
  #pragma unroll
  for(int m=0;m<8;m++){ acc[m][0] = (f32x4)0.f; acc[m][1] = (f32x4)0.f; }
  #pragma unroll
  for(int m=0; m<8; m++){
    const ushort* ap = lds_a + (m*16 + lc)*136 + lk*8;
    #pragma unroll
    for(int s=0; s<4; s++){
      short8 a = *(const short8*)(ap + s*32);
      acc[m][0] = __builtin_amdgcn_mfma_f32_16x16x32_bf16(a, bfrag[0][s], acc[m][0], 0, 0, 0);
      acc[m][1] = __builtin_amdgcn_mfma_f32_16x16x32_bf16(a, bfrag[1][s], acc[m][1], 0, 0, 0);
    }
  }
  #pragma unroll
  for(int m=0; m<8; m++){
    #pragma unroll
    for(int tt=0; tt<2; tt++){
      int colg = wv*32 + tt*16 + lc;
      #pragma unroll
      for(int r=0; r<4; r++){
        int row = m*16 + lk*4 + r;
        int node = row0 + row;
        if(node < NN)
          g[(size_t)node*128 + colg] = f2b(acc[m][tt][r] * sdinv[row]);
      }
    }
  }
}

__global__ __launch_bounds__(256)
void k_agg(const ushort* __restrict__ g, const int* __restrict__ rowstart,
           const int* __restrict__ srcs, const float* __restrict__ dinv,
           const float* __restrict__ bias, ushort* __restrict__ outp)
{
  const int lane = threadIdx.x & 31;
  const int node = blockIdx.x*8 + (threadIdx.x >> 5);
  const int e0 = rowstart[node], e1 = rowstart[node+1];
  float ax=0.f, ay=0.f, az=0.f, aw=0.f;
  float bx=0.f, by=0.f, bz=0.f, bw=0.f;
  const ushort4* gp = (const ushort4*)g;
  int e = e0;
  for(; e+7 < e1; e += 8){
    int si[8];
    #pragma unroll
    for(int i=0;i<8;i++) si[i] = srcs[e+i];
    ushort4 v[8];
    #pragma unroll
    for(int i=0;i<8;i++) v[i] = gp[(size_t)si[i]*32 + lane];
    #pragma unroll
    for(int i=0;i<8;i++){
      if(i&1){ bx += b2f(v[i].x); by += b2f(v[i].y); bz += b2f(v[i].z); bw += b2f(v[i].w); }
      else   { ax += b2f(v[i].x); ay += b2f(v[i].y); az += b2f(v[i].z); aw += b2f(v[i].w); }
    }
  }
  for(; e+3 < e1; e += 4){
    int si[4];
    #pragma unroll
    for(int i=0;i<4;i++) si[i] = srcs[e+i];
    ushort4 v[4];
    #pragma unroll
    for(int i=0;i<4;i++) v[i] = gp[(size_t)si[i]*32 + lane];
    #pragma unroll
    for(int i=0;i<4;i++){
      if(i&1){ bx += b2f(v[i].x); by += b2f(v[i].y); bz += b2f(v[i].z); bw += b2f(v[i].w); }
      else   { ax += b2f(v[i].x); ay += b2f(v[i].y); az += b2f(v[i].z); aw += b2f(v[i].w); }
    }
  }
  for(; e < e1; e++){
    ushort4 v = gp[(size_t)srcs[e]*32 + lane];
    ax += b2f(v.x); ay += b2f(v.y); az += b2f(v.z); aw += b2f(v.w);
  }
  ushort4 vs = gp[(size_t)node*32 + lane];
  float dv = dinv[node];
  float4 bv = ((const float4*)bias)[lane];
  ushort4 o4;
  o4.x = f2b(dv*(ax+bx+b2f(vs.x))+bv.x);
  o4.y = f2b(dv*(ay+by+b2f(vs.y))+bv.y);
  o4.z = f2b(dv*(az+bz+b2f(vs.z))+bv.z);
  o4.w = f2b(dv*(aw+bw+b2f(vs.w))+bv.w);
  ((ushort4*)outp)[(size_t)node*32 + lane] = o4;
}

__global__ __launch_bounds__(128)
void k_stats(const ushort* __restrict__ x, const int* __restrict__ gstart,
             float* __restrict__ S1, float* __restrict__ S2)
{
  int g = blockIdx.x, ch = blockIdx.y, f = threadIdx.x;
  int s = gstart[g], e = gstart[g+1];
  int len = e - s;
  int i0 = s + (int)((long long)len * ch / STAT_CH);
  int i1 = s + (int)((long long)len * (ch+1) / STAT_CH);
  float a1 = 0.f, a2 = 0.f;
  for(int n=i0; n<i1; n++){
    float v = b2f(x[(size_t)n*128 + f]);
    a1 += v; a2 += v*v;
  }
  if(i1 > i0){
    atomicAdd(&S1[g*128+f], a1);
    atomicAdd(&S2[g*128+f], a2);
  }
}

__global__ __launch_bounds__(128)
void k_pool(const ushort* __restrict__ x, const int* __restrict__ gstart,
            const float* __restrict__ gw, const float* __restrict__ gb,
            const float* __restrict__ ga, const float* __restrict__ S1,
            const float* __restrict__ S2, float* __restrict__ pooled)
{
  int g = blockIdx.x, ch = blockIdx.y, f = threadIdx.x;
  int s = gstart[g], e = gstart[g+1];
  int len = e - s;
  int i0 = s + (int)((long long)len * ch / POOL_CH);
  int i1 = s + (int)((long long)len * (ch+1) / POOL_CH);
  float inv = 1.f/(float)(len > 0 ? len : 1);
  float a = ga[f];
  float m = S1[g*128+f]*inv, ex2 = S2[g*128+f]*inv;
  float am = a*m;
  float rs = rsqrtf(ex2 - (2.f*a - a*a)*m*m + EPSV);
  float wv = gw[f], bv = gb[f];
  float a1 = 0.f;
  for(int n=i0; n<i1; n++){
    float v = b2f(x[(size_t)n*128 + f]);
    v = wv*(v-am)*rs + bv;
    a1 += fmaxf(v, 0.f);
  }
  if(i1 > i0) atomicAdd(&pooled[g*128+f], a1);
}

__global__ __launch_bounds__(64)
void k_head(const float* __restrict__ pooled, const int* __restrict__ gstart,
            const float* __restrict__ lw, const float* __restrict__ lb,
            float* __restrict__ out)
{
  int g = blockIdx.x, t = threadIdx.x;
  __shared__ float lg[NC];
  __shared__ float lse_s;
  int len = gstart[g+1] - gstart[g];
  float inv = 1.f/(float)(len > 0 ? len : 1);
  if(t < NC){
    float acc = lb[t];
    for(int f=0; f<128; f++) acc += pooled[g*128+f]*inv*lw[f*NC + t];
    lg[t] = acc;
  }
  __syncthreads();
  if(t == 0){
    float mx = -1e30f;
    for(int c=0;c<NC;c++) mx = fmaxf(mx, lg[c]);
    float sm = 0.f;
    for(int c=0;c<NC;c++) sm += expf(lg[c]-mx);
    lse_s = mx + logf(sm);
  }
  __syncthreads();
  if(t < NC) out[g*NC + t] = lg[t] - lse_s;
}

// ============================================================================================
// Cooperative kernels
// ============================================================================================

__global__ __launch_bounds__(256)
void k_prep(const int* __restrict__ ei, const int* __restrict__ batch, int* __restrict__ gstart,
            const float* __restrict__ w1, const float* __restrict__ w2, const float* __restrict__ w3,
            ushort* __restrict__ wT, int* __restrict__ gbhist, float* __restrict__ zero_base,
            int* __restrict__ bucket_base, int* __restrict__ bucket_cursor, int* __restrict__ rowstart,
            unsigned* __restrict__ ebuf, int* __restrict__ srcs, float* __restrict__ dinv)
{
  __shared__ unsigned eb[4096];
  __shared__ unsigned char bb4[4096];
  __shared__ int hist[512];
  __shared__ int cur[512];
  __shared__ int lstart[NBKT];
  __shared__ int rbase[NBKT];
  __shared__ int scanbuf[256];
  cg::grid_group grid = cg::this_grid();
  const int t = threadIdx.x;

  for(int vb = blockIdx.x; vb < 409; vb += gridDim.x)
    init_body(vb, t, batch, gstart, w1, w2, w3, wT, gbhist, zero_base);
  grid.sync();

  for(int vb = blockIdx.x; vb < BIN_BLOCKS; vb += gridDim.x){
    if(t < NBKT) hist[t] = 0;
    __syncthreads();
    int base = vb*4096;
    #pragma unroll
    for(int i=0;i<16;i++){
      int e = base + i*256 + t;
      if(e < NE) atomicAdd(&hist[ei[NE + e] >> BSH], 1);
    }
    __syncthreads();
    if(t < NBKT && hist[t]) atomicAdd(&gbhist[t], hist[t]);
    __syncthreads();
  }
  grid.sync();

  if(blockIdx.x == 0){
    int v = (t < NBKT) ? gbhist[t] : 0;
    scanbuf[t] = v; __syncthreads();
    for(int off=1; off<256; off<<=1){
      int y = scanbuf[t]; int z = (t>=off)?scanbuf[t-off]:0;
      __syncthreads(); scanbuf[t] = y+z; __syncthreads();
    }
    int excl = (t>0)?scanbuf[t-1]:0;
    if(t < NBKT){ bucket_base[t] = excl; bucket_cursor[t] = excl; }
    if(t == 0){ bucket_base[NBKT] = NE; rowstart[NN] = NE; }
  }
  grid.sync();

  for(int vb = blockIdx.x; vb < BIN_BLOCKS; vb += gridDim.x){
    if(t < NBKT) hist[t] = 0;
    __syncthreads();
    int base = vb*4096;
    int nv = NE - base; if(nv > 4096) nv = 4096;
    int se[16], de[16];
    #pragma unroll
    for(int i=0;i<16;i++){
      int e = base + i*256 + t;
      if(e < NE){ se[i] = ei[e]; de[i] = ei[NE + e]; atomicAdd(&hist[de[i] >> BSH], 1); }
    }
    __syncthreads();
    int v = (t < NBKT) ? hist[t] : 0;
    scanbuf[t] = v; __syncthreads();
    for(int off=1; off<256; off<<=1){
      int y = scanbuf[t]; int z = (t>=off)?scanbuf[t-off]:0;
      __syncthreads(); scanbuf[t] = y+z; __syncthreads();
    }
    if(t < NBKT){
      int excl = (t>0)?scanbuf[t-1]:0;
      lstart[t] = excl; cur[t] = excl;
      if(hist[t]) rbase[t] = atomicAdd(&bucket_cursor[t], hist[t]);
    }
    __syncthreads();
    #pragma unroll
    for(int i=0;i<16;i++){
      int e = base + i*256 + t;
      if(e < NE){
        int b = de[i] >> BSH;
        int idx = atomicAdd(&cur[b], 1);
        eb[idx] = ((unsigned)(de[i] & 511) << 17) | (unsigned)se[i];
        bb4[idx] = (unsigned char)b;
      }
    }
    __syncthreads();
    #pragma unroll
    for(int i=0;i<16;i++){
      int slot = i*256 + t;
      if(slot < nv){
        int b = bb4[slot];
        ebuf[rbase[b] + (slot - lstart[b])] = eb[slot];
      }
    }
    __syncthreads();
  }
  grid.sync();

  for(int vb = blockIdx.x; vb < NBKT; vb += gridDim.x){
    int e0 = bucket_base[vb], e1 = bucket_base[vb+1];
    hist[t] = 0; hist[t+256] = 0;
    __syncthreads();
    for(int i = e0 + t; i < e1; i += 256)
      atomicAdd(&hist[ebuf[i] >> 17], 1);
    __syncthreads();
    int s0 = hist[2*t], s1 = hist[2*t+1];
    scanbuf[t] = s0 + s1; __syncthreads();
    for(int off=1; off<256; off<<=1){
      int y = scanbuf[t]; int z = (t>=off)?scanbuf[t-off]:0;
      __syncthreads(); scanbuf[t] = y+z; __syncthreads();
    }
    int excl = (t>0)?scanbuf[t-1]:0;
    cur[2*t] = excl; cur[2*t+1] = excl + s0;
    int d0 = (vb << BSH) + 2*t, d1 = d0 + 1;
    if(d0 < NN){ rowstart[d0] = e0 + excl;      dinv[d0] = rsqrtf((float)(s0 + 1)); }
    if(d1 < NN){ rowstart[d1] = e0 + excl + s0; dinv[d1] = rsqrtf((float)(s1 + 1)); }
    __syncthreads();
    for(int i = e0 + t; i < e1; i += 256){
      unsigned pk = ebuf[i];
      int dl = pk >> 17;
      int pos = e0 + atomicAdd(&cur[dl], 1);
      srcs[pos] = (int)(pk & 0x1FFFFu);
    }
    __syncthreads();
  }
}

template<int NORM, int LAST>
__global__ __launch_bounds__(256, 4)
void k_layer(const void* in_, const ushort* __restrict__ wTl,
             ushort* gbuf, ushort* outB,
             const float* __restrict__ dinv, const int* __restrict__ batch,
             const int* __restrict__ gstart, const int* __restrict__ rowstart,
             const int* __restrict__ srcs, const float* __restrict__ bias,
             const float* __restrict__ gw, const float* __restrict__ gb,
             const float* __restrict__ ga, const float* S1p, const float* S2p,
             float* S1c, float* S2c,
             const float* __restrict__ pw, const float* __restrict__ pb,
             const float* __restrict__ pa, float* __restrict__ pooled,
             const float* __restrict__ lw, const float* __restrict__ lb,
             float* __restrict__ out)
{
  __shared__ ushort lds_a[64*136];
  __shared__ float sdinv[64];
  __shared__ float shead[NC+1];
  cg::grid_group grid = cg::this_grid();
  const int t = threadIdx.x;
  const int wv = t >> 6, l = t & 63, lc = l & 15, lk = l >> 4;

  short8 bfrag[2][4];
  #pragma unroll
  for(int tt=0; tt<2; tt++){
    int col = wv*32 + tt*16 + lc;
    #pragma unroll
    for(int s=0; s<4; s++)
      bfrag[tt][s] = *(const short8*)(wTl + col*128 + s*32 + lk*8);
  }

  // ---- phase A: GEMM over 64-row tiles ----
  for(int tile = blockIdx.x; tile < (NN+63)/64; tile += gridDim.x){
    const int row0 = tile * 64;
    {
      const int sl = t & 31;
      const int rr = t >> 5;
      if(t < 64){
        int node = row0 + t;
        sdinv[t] = (node < NN) ? dinv[node] : 0.f;
      }
      float4 gwv, gbv, gav;
      float4 amv = make_float4(0.f,0.f,0.f,0.f), rsv = make_float4(0.f,0.f,0.f,0.f);
      int gprev = -1;
      if(NORM){
        gwv = ((const float4*)gw)[sl]; gbv = ((const float4*)gb)[sl];
        gav = ((const float4*)ga)[sl];
      }
      #pragma unroll 4
      for(int rb = 0; rb < 8; rb++){
        int r = rb*8 + rr;
        int node = row0 + r;
        float4 v = make_float4(0.f,0.f,0.f,0.f);
        if(node < NN){
          if(NORM){
            ushort4 raw = ((const ushort4*)in_)[(size_t)node*32 + sl];
            v = make_float4(b2f(raw.x), b2f(raw.y), b2f(raw.z), b2f(raw.w));
            int gg = batch[node];
            if(gg != gprev){
              gprev = gg;
              int c0 = gstart[gg], c1 = gstart[gg+1];
              float inv = 1.f/(float)((c1-c0) > 0 ? (c1-c0) : 1);
              float4 s1v = ((const float4*)S1p)[gg*32 + sl];
              float4 s2v = ((const float4*)S2p)[gg*32 + sl];
              float m, ex2, a;
              m = s1v.x*inv; ex2 = s2v.x*inv; a = gav.x;
              amv.x = a*m; rsv.x = rsqrtf(ex2 - (2.f*a - a*a)*m*m + EPSV);
              m = s1v.y*inv; ex2 = s2v.y*inv; a = gav.y;
              amv.y = a*m; rsv.y = rsqrtf(ex2 - (2.f*a - a*a)*m*m + EPSV);
              m = s1v.z*inv; ex2 = s2v.z*inv; a = gav.z;
              amv.z = a*m; rsv.z = rsqrtf(ex2 - (2.f*a - a*a)*m*m + EPSV);
              m = s1v.w*inv; ex2 = s2v.w*inv; a = gav.w;
              amv.w = a*m; rsv.w = rsqrtf(ex2 - (2.f*a - a*a)*m*m + EPSV);
            }
            v.x = fmaxf(gwv.x*(v.x-amv.x)*rsv.x + gbv.x, 0.f);
            v.y = fmaxf(gwv.y*(v.y-amv.y)*rsv.y + gbv.y, 0.f);
            v.z = fmaxf(gwv.z*(v.z-amv.z)*rsv.z + gbv.z, 0.f);
            v.w = fmaxf(gwv.w*(v.w-amv.w)*rsv.w + gbv.w, 0.f);
          } else {
            v = ((const float4*)in_)[(size_t)node*32 + sl];
          }
        }
        ushort4 b4;
        b4.x = f2b(v.x); b4.y = f2b(v.y); b4.z = f2b(v.z); b4.w = f2b(v.w);
        *(ushort4*)(lds_a + r*136 + sl*4) = b4;
      }
    }
    __syncthreads();

    f32x4 acc[4][2];
    #pragma unroll
    for(int m=0;m<4;m++){ acc[m][0] = (f32x4)0.f; acc[m][1] = (f32x4)0.f; }
    #pragma unroll
    for(int m=0; m<4; m++){
      const ushort* ap = lds_a + (m*16 + lc)*136 + lk*8;
      #pragma unroll
      for(int s=0; s<4; s++){
        short8 a = *(const short8*)(ap + s*32);
        acc[m][0] = __builtin_amdgcn_mfma_f32_16x16x32_bf16(a, bfrag[0][s], acc[m][0], 0, 0, 0);
        acc[m][1] = __builtin_amdgcn_mfma_f32_16x16x32_bf16(a, bfrag[1][s], acc[m][1], 0, 0, 0);
      }
    }
    #pragma unroll
    for(int m=0; m<4; m++){
      #pragma unroll
      for(int tt=0; tt<2; tt++){
        int colg = wv*32 + tt*16 + lc;
        #pragma unroll
        for(int r=0; r<4; r++){
          int row = m*16 + lk*4 + r;
          int node = row0 + row;
          if(node < NN)
            gbuf[(size_t)node*128 + colg] = f2b(acc[m][tt][r] * sdinv[row]);
        }
      }
    }
    __syncthreads();
  }
  grid.sync();

  // ---- phase B: aggregation ----
  {
    const int lane = t & 31;
    const ushort4* gp = (const ushort4*)gbuf;
    for(int grp = blockIdx.x; grp < NN/8; grp += gridDim.x){
      const int node = grp*8 + (t >> 5);
      const int e0 = rowstart[node], e1 = rowstart[node+1];
      float ax=0.f, ay=0.f, az=0.f, aw=0.f;
      float bx=0.f, by=0.f, bz=0.f, bw=0.f;
      int e = e0;
      for(; e+7 < e1; e += 8){
        int si[8];
        #pragma unroll
        for(int i=0;i<8;i++) si[i] = srcs[e+i];
        ushort4 v[8];
        #pragma unroll
        for(int i=0;i<8;i++) v[i] = gp[(size_t)si[i]*32 + lane];
        #pragma unroll
        for(int i=0;i<8;i++){
          if(i&1){ bx += b2f(v[i].x); by += b2f(v[i].y); bz += b2f(v[i].z); bw += b2f(v[i].w); }
          else   { ax += b2f(v[i].x); ay += b2f(v[i].y); az += b2f(v[i].z); aw += b2f(v[i].w); }
        }
      }
      for(; e+3 < e1; e += 4){
        int si[4];
        #pragma unroll
        for(int i=0;i<4;i++) si[i] = srcs[e+i];
        ushort4 v[4];
        #pragma unroll
        for(int i=0;i<4;i++) v[i] = gp[(size_t)si[i]*32 + lane];
        #pragma unroll
        for(int i=0;i<4;i++){
          if(i&1){ bx += b2f(v[i].x); by += b2f(v[i].y); bz += b2f(v[i].z); bw += b2f(v[i].w); }
          else   { ax += b2f(v[i].x); ay += b2f(v[i].y); az += b2f(v[i].z); aw += b2f(v[i].w); }
        }
      }
      for(; e < e1; e++){
        ushort4 v = gp[(size_t)srcs[e]*32 + lane];
        ax += b2f(v.x); ay += b2f(v.y); az += b2f(v.z); aw += b2f(v.w);
      }
      ushort4 vs = gp[(size_t)node*32 + lane];
      float dv = dinv[node];
      float4 bv = ((const float4*)bias)[lane];
      ushort4 o4;
      o4.x = f2b(dv*(ax+bx+b2f(vs.x))+bv.x);
      o4.y = f2b(dv*(ay+by+b2f(vs.y))+bv.y);
      o4.z = f2b(dv*(az+bz+b2f(vs.z))+bv.z);
      o4.w = f2b(dv*(aw+bw+b2f(vs.w))+bv.w);
      ((ushort4*)outB)[(size_t)node*32 + lane] = o4;
    }
  }
  grid.sync();

  // ---- phase C: stats ----
  {
    const int f = t & 127, sub = t >> 7;
    for(int idx = blockIdx.x; idx < NG*STAT_CH; idx += gridDim.x){
      int g = idx >> 3, ch = idx & 7;
      int s = gstart[g], e = gstart[g+1];
      int len = e - s;
      int i0 = s + (int)((long long)len * ch / STAT_CH);
      int i1 = s + (int)((long long)len * (ch+1) / STAT_CH);
      float a1 = 0.f, a2 = 0.f;
      for(int n = i0 + sub; n < i1; n += 2){
        float v = b2f(outB[(size_t)n*128 + f]);
        a1 += v; a2 += v*v;
      }
      if(i1 > i0){
        atomicAdd(&S1c[g*128+f], a1);
        atomicAdd(&S2c[g*128+f], a2);
      }
    }
  }

  if(LAST){
    grid.sync();
    {
      const int f = t & 127, sub = t >> 7;
      for(int idx = blockIdx.x; idx < NG*POOL_CH; idx += gridDim.x){
        int g = idx >> 4, ch = idx & 15;
        int s = gstart[g], e = gstart[g+1];
        int len = e - s;
        int i0 = s + (int)((long long)len * ch / POOL_CH);
        int i1 = s + (int)((long long)len * (ch+1) / POOL_CH);
        float inv = 1.f/(float)(len > 0 ? len : 1);
        float a = pa[f];
        float m = S1c[g*128+f]*inv, ex2 = S2c[g*128+f]*inv;
        float am = a*m;
        float rs = rsqrtf(ex2 - (2.f*a - a*a)*m*m + EPSV);
        float wvv = pw[f], bvv = pb[f];
        float a1 = 0.f;
        for(int n = i0 + sub; n < i1; n += 2){
          float v = b2f(outB[(size_t)n*128 + f]);
          v = wvv*(v-am)*rs + bvv;
          a1 += fmaxf(v, 0.f);
        }
        if(i1 > i0) atomicAdd(&pooled[g*128+f], a1);
      }
    }
    grid.sync();
    for(int g = blockIdx.x; g < NG; g += gridDim.x){
      int len = gstart[g+1] - gstart[g];
      float inv = 1.f/(float)(len > 0 ? len : 1);
      if(t < NC){
        float acc = lb[t];
        for(int f2=0; f2<128; f2++) acc += pooled[g*128+f2]*inv*lw[f2*NC + t];
        shead[t] = acc;
      }
      __syncthreads();
      if(t == 0){
        float mx = -1e30f;
        for(int c=0;c<NC;c++) mx = fmaxf(mx, shead[c]);
        float sm = 0.f;
        for(int c=0;c<NC;c++) sm += expf(shead[c]-mx);
        shead[NC] = mx + logf(sm);
      }
      __syncthreads();
      if(t < NC) out[g*NC + t] = shead[t] - shead[NC];
      __syncthreads();
    }
  }
}

// ============================================================================================
// Launch: cooperative with occupancy-validated grids; per-stage fallback to classic path
// ============================================================================================
extern "C" void kernel_launch(void* const* d_in, const int* in_sizes, int n_in,
                              void* d_out, int out_size, void* d_ws, size_t ws_size,
                              hipStream_t stream)
{
  const float* x    = (const float*)d_in[0];
  const int*   ei   = (const int*)d_in[1];
  const int*   batch= (const int*)d_in[2];
  const float* w1   = (const float*)d_in[3];
  const float* b1   = (const float*)d_in[4];
  const float* w2   = (const float*)d_in[5];
  const float* b2   = (const float*)d_in[6];
  const float* w3   = (const float*)d_in[7];
  const float* b3   = (const float*)d_in[8];
  const float* g1w  = (const float*)d_in[9];
  const float* g1b  = (const float*)d_in[10];
  const float* g1a  = (const float*)d_in[11];
  const float* g2w  = (const float*)d_in[12];
  const float* g2b  = (const float*)d_in[13];
  const float* g2a  = (const float*)d_in[14];
  const float* g3w  = (const float*)d_in[15];
  const float* g3b  = (const float*)d_in[16];
  const float* g3a  = (const float*)d_in[17];
  const float* lw   = (const float*)d_in[18];
  const float* lb   = (const float*)d_in[19];
  float* out = (float*)d_out;

  char* p = (char*)d_ws;
  auto take = [&](size_t nbytes){ char* q = p; p += (nbytes + 255) & ~(size_t)255; return q; };
  ushort* gbuf    = (ushort*)take((size_t)NN*HD*2);
  ushort* bufB    = (ushort*)take((size_t)NN*HD*2);
  ushort* wT      = (ushort*)take((size_t)3*HD*HD*2);
  unsigned* ebuf  = (unsigned*)take((size_t)NE*4);
  int*   srcs     = (int*)  take((size_t)NE*4);
  int*   rowstart = (int*)  take((size_t)(NN+1)*4);
  float* dinv     = (float*)take((size_t)NN*4);
  int*   gbhist   = (int*)  take((size_t)NBKT*4);
  int*   bucket_base   = (int*)take((size_t)(NBKT+1)*4);
  int*   bucket_cursor = (int*)take((size_t)NBKT*4);
  int*   gstart   = (int*)  take((size_t)(NG+1)*4);
  float* Sbase    = (float*)take((size_t)(3*2*NG*HD + NG*HD)*4);
  if((size_t)(p - (char*)d_ws) > ws_size) return;

  float* SL1  = Sbase;
  float* SL1b = Sbase + 1*NG*HD;
  float* SL2  = Sbase + 2*NG*HD;
  float* SL2b = Sbase + 3*NG*HD;
  float* SL3  = Sbase + 4*NG*HD;
  float* SL3b = Sbase + 5*NG*HD;
  float* pooled = Sbase + 6*NG*HD;

  // occupancy-derived cooperative grid sizes (deterministic host queries)
  int nbP = 0, nbL0 = 0, nbL1 = 0, nbL2 = 0;
  (void)hipOccupancyMaxActiveBlocksPerMultiprocessor(&nbP,  k_prep,        256, 0);
  (void)hipOccupancyMaxActiveBlocksPerMultiprocessor(&nbL0, k_layer<0,0>,  256, 0);
  (void)hipOccupancyMaxActiveBlocksPerMultiprocessor(&nbL1, k_layer<1,0>,  256, 0);
  (void)hipOccupancyMaxActiveBlocksPerMultiprocessor(&nbL2, k_layer<1,1>,  256, 0);
  int nbL = nbL0 < nbL1 ? nbL0 : nbL1; if(nbL2 < nbL) nbL = nbL2;
  const int NCU = 256;
  long long capL = (long long)nbL * NCU;
  int GL = (int)(capL < 2048 ? capL : 2048);

  // ---- preprocessing ----
  bool prep_ok = false;
  if(nbP > 0 && (long long)nbP * NCU >= 409){
    void* args[] = {(void*)&ei, (void*)&batch, (void*)&gstart, (void*)&w1, (void*)&w2,
                    (void*)&w3, (void*)&wT, (void*)&gbhist, (void*)&Sbase,
                    (void*)&bucket_base, (void*)&bucket_cursor, (void*)&rowstart,
                    (void*)&ebuf, (void*)&srcs, (void*)&dinv};
    prep_ok = (hipLaunchCooperativeKernel(k_prep, dim3(409), dim3(256), args, 0, stream) == hipSuccess);
  }
  if(!prep_ok){
    k_init  <<<409, 256, 0, stream>>>(batch, gstart, w1, w2, w3, wT, gbhist, Sbase);
    k_bhist <<<BIN_BLOCKS, 256, 0, stream>>>(ei, gbhist);
    k_bscan <<<1, 256, 0, stream>>>(gbhist, bucket_base, bucket_cursor, rowstart);
    k_bin   <<<BIN_BLOCKS, 256, 0, stream>>>(ei, bucket_cursor, ebuf);
    k_sort  <<<NBKT, 256, 0, stream>>>(ebuf, bucket_base, srcs, rowstart, dinv);
  }

  const int GB = (NN + 127)/128;     // classic gemm grid
  const int AB = NN/8;               // classic agg grid

  // ---- layer 1 ----
  bool ok = false;
  if(GL > 0){
    const void* inp = (const void*)x;
    const ushort* wTl = wT;
    void* args[] = {(void*)&inp, (void*)&wTl, (void*)&gbuf, (void*)&bufB, (void*)&dinv,
                    (void*)&batch, (void*)&gstart, (void*)&rowstart, (void*)&srcs, (void*)&b1,
                    (void*)&g1w, (void*)&g1b, (void*)&g1a, (void*)&SL1, (void*)&SL1b,
                    (void*)&SL1, (void*)&SL1b, (void*)&g3w, (void*)&g3b, (void*)&g3a,
                    (void*)&pooled, (void*)&lw, (void*)&lb, (void*)&out};
    ok = (hipLaunchCooperativeKernel(k_layer<0,0>, dim3(GL), dim3(256), args, 0, stream) == hipSuccess);
  }
  if(!ok){
    k_gemm<0><<<GB, 256, 0, stream>>>(x, wT, gbuf, dinv, batch,
                                      nullptr, nullptr, nullptr, nullptr, nullptr, gstart);
    k_agg<<<AB, 256, 0, stream>>>(gbuf, rowstart, srcs, dinv, b1, bufB);
    k_stats<<<dim3(NG, STAT_CH), 128, 0, stream>>>(bufB, gstart, SL1, SL1b);
  }

  // ---- layer 2 ----
  ok = false;
  if(GL > 0){
    const void* inp = (const void*)bufB;
    const ushort* wTl = wT + 16384;
    void* args[] = {(void*)&inp, (void*)&wTl, (void*)&gbuf, (void*)&bufB, (void*)&dinv,
                    (void*)&batch, (void*)&gstart, (void*)&rowstart, (void*)&srcs, (void*)&b2,
                    (void*)&g1w, (void*)&g1b, (void*)&g1a, (void*)&SL1, (void*)&SL1b,
                    (void*)&SL2, (void*)&SL2b, (void*)&g3w, (void*)&g3b, (void*)&g3a,
                    (void*)&pooled, (void*)&lw, (void*)&lb, (void*)&out};
    ok = (hipLaunchCooperativeKernel(k_layer<1,0>, dim3(GL), dim3(256), args, 0, stream) == hipSuccess);
  }
  if(!ok){
    k_gemm<1><<<GB, 256, 0, stream>>>(bufB, wT + 16384, gbuf, dinv, batch,
                                      g1w, g1b, g1a, SL1, SL1b, gstart);
    k_agg<<<AB, 256, 0, stream>>>(gbuf, rowstart, srcs, dinv, b2, bufB);
    k_stats<<<dim3(NG, STAT_CH), 128, 0, stream>>>(bufB, gstart, SL2, SL2b);
  }

  // ---- layer 3 (+ pool + head) ----
  ok = false;
  if(GL > 0){
    const void* inp = (const void*)bufB;
    const ushort* wTl = wT + 32768;
    void* args[] = {(void*)&inp, (void*)&wTl, (void*)&gbuf, (void*)&bufB, (void*)&dinv,
                    (void*)&batch, (void*)&gstart, (void*)&rowstart, (void*)&srcs, (void*)&b3,
                    (void*)&g2w, (void*)&g2b, (void*)&g2a, (void*)&SL2, (void*)&SL2b,
                    (void*)&SL3, (void*)&SL3b, (void*)&g3w, (void*)&g3b, (void*)&g3a,
                    (void*)&pooled, (void*)&lw, (void*)&lb, (void*)&out};
    ok = (hipLaunchCooperativeKernel(k_layer<1,1>, dim3(GL), dim3(256), args, 0, stream) == hipSuccess);
  }
  if(!ok){
    k_gemm<1><<<GB, 256, 0, stream>>>(bufB, wT + 32768, gbuf, dinv, batch,
                                      g2w, g2b, g2a, SL2, SL2b, gstart);
    k_agg<<<AB, 256, 0, stream>>>(gbuf, rowstart, srcs, dinv, b3, bufB);
    k_stats<<<dim3(NG, STAT_CH), 128, 0, stream>>>(bufB, gstart, SL3, SL3b);
    k_pool<<<dim3(NG, POOL_CH), 128, 0, stream>>>(bufB, gstart, g3w, g3b, g3a, SL3, SL3b, pooled);
    k_head<<<NG, 64, 0, stream>>>(pooled, gstart, lw, lb, out);
  }
}

// Round 10
// 482.829 us; speedup vs baseline: 2.6588x; 2.6588x over previous
//
#include <hip/hip_runtime.h>

#define NN 100000
#define NE 1600000
#define HD 128
#define NG 128
#define NC 10
#define EPSV 1e-5f

#define BSH 9                      // 512 dst nodes per bucket
#define NBKT ((NN + 511) >> 9)     // 196
#define BCAP 9216                  // slots per bucket region (mean 8192, sigma~90 -> +11 sigma)
#define BIN_BLOCKS ((NE + 4095) / 4096)  // 391
#define STAT_CH 8
#define POOL_CH 16

typedef __attribute__((ext_vector_type(8))) short short8;
typedef __attribute__((ext_vector_type(4))) float f32x4;

__device__ __forceinline__ float b2f(ushort u){ return __uint_as_float(((unsigned)u)<<16); }
__device__ __forceinline__ ushort f2b(float f){
  unsigned u = __float_as_uint(f);
  unsigned r = (u + 0x7FFFu + ((u>>16)&1u)) >> 16;   // RNE
  return (ushort)r;
}

// ---------------- init: granges + weight-prep + zeroing (S, cursor0, done) ----------------
// blocks 0..390: granges | 391..393: wT | 394..407: zero S+pooled | 408: cursor0/done/rowstart[NN]
__global__ __launch_bounds__(256)
void k_init(const int* __restrict__ batch, int* __restrict__ gstart,
            const float* __restrict__ w1, const float* __restrict__ w2,
            const float* __restrict__ w3, ushort* __restrict__ wT,
            int* __restrict__ cursor0, int* __restrict__ done,
            int* __restrict__ rowstart, float* __restrict__ zero_base)
{
  int b = blockIdx.x, t = threadIdx.x;
  if(b < 391){                       // granges: batch sorted -> contiguous segments
    int n = b*256 + t;
    if(n >= NN) return;
    int bb = batch[n];
    if(n == 0){
      for(int g=0; g<=bb; g++) gstart[g] = 0;
      int last = batch[NN-1];
      for(int g=last+1; g<=NG; g++) gstart[g] = NN;
    } else {
      int bp = batch[n-1];
      for(int g=bp+1; g<=bb; g++) gstart[g] = n;
    }
  } else if(b < 394){                // wT[layer][h][k] = bf16(w[k][h])
    const float* w = (b == 391) ? w1 : (b == 392) ? w2 : w3;
    ushort* o = wT + (b-391)*16384;
    #pragma unroll 4
    for(int i=0;i<64;i++){
      int e = i*256 + t;
      o[(e & 127)*128 + (e >> 7)] = f2b(w[e]);
    }
  } else if(b < 408){                // zero 3x(S1,S2)+pooled = 114688 floats
    #pragma unroll 8
    for(int i=0;i<32;i++) zero_base[(size_t)(b-394)*8192 + i*256 + t] = 0.f;
  } else {
    if(t < NBKT) cursor0[t] = 0;
    if(t < NG)   done[t] = 0;
    if(t == 0)   rowstart[NN] = NE;
  }
}

// ---------------- bin: edges -> per-bucket regions (LDS-staged, contiguous writes) ----------
// record = (dst_local:9 << 17) | src:17 ; region b occupies ebuf[b*BCAP ...]
__global__ __launch_bounds__(256) void k_bin(const int* __restrict__ ei, int* __restrict__ cursor0,
                                             unsigned* __restrict__ ebuf){
  __shared__ unsigned eb[4096];
  __shared__ unsigned char bb4[4096];
  __shared__ int hist[NBKT], lstart[NBKT], lcur[NBKT], rbase[NBKT];
  __shared__ int scanbuf[256];
  int t = threadIdx.x;
  if(t < NBKT) hist[t] = 0;
  __syncthreads();
  int base = blockIdx.x*4096;
  int nv = NE - base; if(nv > 4096) nv = 4096;
  int se[16], de[16];
  #pragma unroll
  for(int i=0;i<16;i++){
    int e = base + i*256 + t;
    if(e < NE){ se[i] = ei[e]; de[i] = ei[NE + e]; atomicAdd(&hist[de[i] >> BSH], 1); }
  }
  __syncthreads();
  int v = (t < NBKT) ? hist[t] : 0;
  scanbuf[t] = v; __syncthreads();
  for(int off=1; off<256; off<<=1){
    int y = scanbuf[t]; int z = (t>=off)?scanbuf[t-off]:0;
    __syncthreads(); scanbuf[t] = y+z; __syncthreads();
  }
  if(t < NBKT){
    int excl = (t>0)?scanbuf[t-1]:0;
    lstart[t] = excl; lcur[t] = excl;
    if(hist[t]) rbase[t] = t*BCAP + atomicAdd(&cursor0[t], hist[t]);
  }
  __syncthreads();
  #pragma unroll
  for(int i=0;i<16;i++){
    int e = base + i*256 + t;
    if(e < NE){
      int b = de[i] >> BSH;
      int idx = atomicAdd(&lcur[b], 1);
      eb[idx] = ((unsigned)(de[i] & 511) << 17) | (unsigned)se[i];
      bb4[idx] = (unsigned char)b;
    }
  }
  __syncthreads();
  #pragma unroll
  for(int i=0;i<16;i++){
    int slot = i*256 + t;
    if(slot < nv){
      int b = bb4[slot];
      ebuf[rbase[b] + (slot - lstart[b])] = eb[slot];
    }
  }
}

// ---------------- sort: per-bucket counting sort -> contiguous CSR (rowstart, srcs, dinv) ----
__global__ __launch_bounds__(256) void k_sort(const unsigned* __restrict__ ebuf,
                                              const int* __restrict__ cursor0,
                                              int* __restrict__ srcs, int* __restrict__ rowstart,
                                              float* __restrict__ dinv){
  __shared__ int hist[512], cur[512];
  __shared__ int scanbuf[256];
  int b = blockIdx.x, t = threadIdx.x;
  // contiguous base for this bucket = exclusive prefix of final counts
  int v = (t < NBKT) ? cursor0[t] : 0;
  scanbuf[t] = v; __syncthreads();
  for(int off=1; off<256; off<<=1){
    int y = scanbuf[t]; int z = (t>=off)?scanbuf[t-off]:0;
    __syncthreads(); scanbuf[t] = y+z; __syncthreads();
  }
  const int e0 = (b>0) ? scanbuf[b-1] : 0;
  const int cnt = cursor0[b];
  const unsigned* reg = ebuf + (size_t)b*BCAP;
  hist[t] = 0; hist[t+256] = 0;
  __syncthreads();
  for(int i = t; i < cnt; i += 256)
    atomicAdd(&hist[reg[i] >> 17], 1);
  __syncthreads();
  int s0 = hist[2*t], s1 = hist[2*t+1];
  scanbuf[t] = s0 + s1; __syncthreads();
  for(int off=1; off<256; off<<=1){
    int y = scanbuf[t]; int z = (t>=off)?scanbuf[t-off]:0;
    __syncthreads(); scanbuf[t] = y+z; __syncthreads();
  }
  int excl = (t>0)?scanbuf[t-1]:0;
  cur[2*t] = excl; cur[2*t+1] = excl + s0;
  int d0 = (b << BSH) + 2*t, d1 = d0 + 1;
  if(d0 < NN){ rowstart[d0] = e0 + excl;      dinv[d0] = rsqrtf((float)(s0 + 1)); }
  if(d1 < NN){ rowstart[d1] = e0 + excl + s0; dinv[d1] = rsqrtf((float)(s1 + 1)); }
  __syncthreads();
  for(int i = t; i < cnt; i += 256){
    unsigned pk = reg[i];
    int dl = pk >> 17;
    int pos = e0 + atomicAdd(&cur[dl], 1);
    srcs[pos] = (int)(pk & 0x1FFFFu);
  }
}

// ---------------- MFMA GEMM: g[node][h] = bf16( dinv[node] * (norm_relu(in[node]) @ w)[h] ) ----
// NORM=0: raw fp32 input (layer 1). NORM=1: bf16 input + GraphNorm (inline from S1/S2) + ReLU.
template<int NORM>
__global__ __launch_bounds__(256)
void k_gemm(const void* __restrict__ in_, const ushort* __restrict__ wT,
            ushort* __restrict__ g, const float* __restrict__ dinv,
            const int* __restrict__ batch,
            const float* __restrict__ gw, const float* __restrict__ gb,
            const float* __restrict__ ga, const float* __restrict__ S1,
            const float* __restrict__ S2, const int* __restrict__ gstart)
{
  __shared__ ushort lds_a[128*136];
  __shared__ float sdinv[128];
  const int t = threadIdx.x;
  const int row0 = blockIdx.x * 128;
  {
    const int l = t & 31;
    const int rr = t >> 5;
    if(t < 128){
      int node = row0 + t;
      sdinv[t] = (node < NN) ? dinv[node] : 0.f;
    }
    float4 gwv, gbv, gav;
    float4 amv = make_float4(0.f,0.f,0.f,0.f), rsv = make_float4(0.f,0.f,0.f,0.f);
    int gprev = -1;
    if(NORM){
      gwv = ((const float4*)gw)[l]; gbv = ((const float4*)gb)[l];
      gav = ((const float4*)ga)[l];
    }
    #pragma unroll 4
    for(int rb = 0; rb < 16; rb++){
      int r = rb*8 + rr;
      int node = row0 + r;
      float4 v = make_float4(0.f,0.f,0.f,0.f);
      if(node < NN){
        if(NORM){
          ushort4 raw = ((const ushort4*)in_)[(size_t)node*32 + l];
          v = make_float4(b2f(raw.x), b2f(raw.y), b2f(raw.z), b2f(raw.w));
          int gg = batch[node];
          if(gg != gprev){
            gprev = gg;
            int c0 = gstart[gg], c1 = gstart[gg+1];
            float inv = 1.f/(float)((c1-c0) > 0 ? (c1-c0) : 1);
            float4 s1v = ((const float4*)S1)[gg*32 + l];
            float4 s2v = ((const float4*)S2)[gg*32 + l];
            float m, ex2, a;
            m = s1v.x*inv; ex2 = s2v.x*inv; a = gav.x;
            amv.x = a*m; rsv.x = rsqrtf(ex2 - (2.f*a - a*a)*m*m + EPSV);
            m = s1v.y*inv; ex2 = s2v.y*inv; a = gav.y;
            amv.y = a*m; rsv.y = rsqrtf(ex2 - (2.f*a - a*a)*m*m + EPSV);
            m = s1v.z*inv; ex2 = s2v.z*inv; a = gav.z;
            amv.z = a*m; rsv.z = rsqrtf(ex2 - (2.f*a - a*a)*m*m + EPSV);
            m = s1v.w*inv; ex2 = s2v.w*inv; a = gav.w;
            amv.w = a*m; rsv.w = rsqrtf(ex2 - (2.f*a - a*a)*m*m + EPSV);
          }
          v.x = fmaxf(gwv.x*(v.x-amv.x)*rsv.x + gbv.x, 0.f);
          v.y = fmaxf(gwv.y*(v.y-amv.y)*rsv.y + gbv.y, 0.f);
          v.z = fmaxf(gwv.z*(v.z-amv.z)*rsv.z + gbv.z, 0.f);
          v.w = fmaxf(gwv.w*(v.w-amv.w)*rsv.w + gbv.w, 0.f);
        } else {
          v = ((const float4*)in_)[(size_t)node*32 + l];
        }
      }
      ushort4 b4;
      b4.x = f2b(v.x); b4.y = f2b(v.y); b4.z = f2b(v.z); b4.w = f2b(v.w);
      *(ushort4*)(lds_a + r*136 + l*4) = b4;
    }
  }
  __syncthreads();

  const int wv = t >> 6, l = t & 63, lc = l & 15, lk = l >> 4;
  short8 bfrag[2][4];
  #pragma unroll
  for(int tt=0; tt<2; tt++){
    int col = wv*32 + tt*16 + lc;
    #pragma unroll
    for(int s=0; s<4; s++)
      bfrag[tt][s] = *(const short8*)(wT + col*128 + s*32 + lk*8);
  }
  f32x4 acc[8][2];
  #pragma unroll
  for(int m=0;m<8;m++){ acc[m][0] = (f32x4)0.f; acc[m][1] = (f32x4)0.f; }
  #pragma unroll
  for(int m=0; m<8; m++){
    const ushort* ap = lds_a + (m*16 + lc)*136 + lk*8;
    #pragma unroll
    for(int s=0; s<4; s++){
      short8 a = *(const short8*)(ap + s*32);
      acc[m][0] = __builtin_amdgcn_mfma_f32_16x16x32_bf16(a, bfrag[0][s], acc[m][0], 0, 0, 0);
      acc[m][1] = __builtin_amdgcn_mfma_f32_16x16x32_bf16(a, bfrag[1][s], acc[m][1], 0, 0, 0);
    }
  }
  #pragma unroll
  for(int m=0; m<8; m++){
    #pragma unroll
    for(int tt=0; tt<2; tt++){
      int colg = wv*32 + tt*16 + lc;
      #pragma unroll
      for(int r=0; r<4; r++){
        int row = m*16 + lk*4 + r;
        int node = row0 + row;
        if(node < NN)
          g[(size_t)node*128 + colg] = f2b(acc[m][tt][r] * sdinv[row]);
      }
    }
  }
}

// ---------------- lean aggregation over dst-sorted edges (bf16 gather + bf16 out) ----------
__global__ __launch_bounds__(256)
void k_agg(const ushort* __restrict__ g, const int* __restrict__ rowstart,
           const int* __restrict__ srcs, const float* __restrict__ dinv,
           const float* __restrict__ bias, ushort* __restrict__ outp)
{
  const int lane = threadIdx.x & 31;
  const int node = blockIdx.x*8 + (threadIdx.x >> 5);
  const int e0 = rowstart[node], e1 = rowstart[node+1];
  float ax=0.f, ay=0.f, az=0.f, aw=0.f;
  float bx=0.f, by=0.f, bz=0.f, bw=0.f;
  const ushort4* gp = (const ushort4*)g;
  int e = e0;
  for(; e+7 < e1; e += 8){
    int si[8];
    #pragma unroll
    for(int i=0;i<8;i++) si[i] = srcs[e+i];
    ushort4 v[8];
    #pragma unroll
    for(int i=0;i<8;i++) v[i] = gp[(size_t)si[i]*32 + lane];
    #pragma unroll
    for(int i=0;i<8;i++){
      if(i&1){ bx += b2f(v[i].x); by += b2f(v[i].y); bz += b2f(v[i].z); bw += b2f(v[i].w); }
      else   { ax += b2f(v[i].x); ay += b2f(v[i].y); az += b2f(v[i].z); aw += b2f(v[i].w); }
    }
  }
  for(; e+3 < e1; e += 4){
    int si[4];
    #pragma unroll
    for(int i=0;i<4;i++) si[i] = srcs[e+i];
    ushort4 v[4];
    #pragma unroll
    for(int i=0;i<4;i++) v[i] = gp[(size_t)si[i]*32 + lane];
    #pragma unroll
    for(int i=0;i<4;i++){
      if(i&1){ bx += b2f(v[i].x); by += b2f(v[i].y); bz += b2f(v[i].z); bw += b2f(v[i].w); }
      else   { ax += b2f(v[i].x); ay += b2f(v[i].y); az += b2f(v[i].z); aw += b2f(v[i].w); }
    }
  }
  for(; e < e1; e++){
    ushort4 v = gp[(size_t)srcs[e]*32 + lane];
    ax += b2f(v.x); ay += b2f(v.y); az += b2f(v.z); aw += b2f(v.w);
  }
  ushort4 vs = gp[(size_t)node*32 + lane];
  float dv = dinv[node];
  float4 bv = ((const float4*)bias)[lane];
  ushort4 o4;
  o4.x = f2b(dv*(ax+bx+b2f(vs.x))+bv.x);
  o4.y = f2b(dv*(ay+by+b2f(vs.y))+bv.y);
  o4.z = f2b(dv*(az+bz+b2f(vs.z))+bv.z);
  o4.w = f2b(dv*(aw+bw+b2f(vs.w))+bv.w);
  ((ushort4*)outp)[(size_t)node*32 + lane] = o4;
}

// ---------------- per-graph moments from bf16 (one pass: sum x, sum x^2) ----------------
__global__ __launch_bounds__(128)
void k_stats(const ushort* __restrict__ x, const int* __restrict__ gstart,
             float* __restrict__ S1, float* __restrict__ S2)
{
  int g = blockIdx.x, ch = blockIdx.y, f = threadIdx.x;
  int s = gstart[g], e = gstart[g+1];
  int len = e - s;
  int i0 = s + (int)((long long)len * ch / STAT_CH);
  int i1 = s + (int)((long long)len * (ch+1) / STAT_CH);
  float a1 = 0.f, a2 = 0.f;
  for(int n=i0; n<i1; n++){
    float v = b2f(x[(size_t)n*128 + f]);
    a1 += v; a2 += v*v;
  }
  if(i1 > i0){
    atomicAdd(&S1[g*128+f], a1);
    atomicAdd(&S2[g*128+f], a2);
  }
}

// ---------------- fused pool + head: 16 blocks/graph; last-done block computes head --------
__global__ __launch_bounds__(128)
void k_poolhead(const ushort* __restrict__ x, const int* __restrict__ gstart,
                const float* __restrict__ gw, const float* __restrict__ gb,
                const float* __restrict__ ga, const float* __restrict__ S1,
                const float* __restrict__ S2, float* __restrict__ pooled,
                int* __restrict__ done,
                const float* __restrict__ lw, const float* __restrict__ lb,
                float* __restrict__ out)
{
  int g = blockIdx.x, ch = blockIdx.y, f = threadIdx.x;
  int s = gstart[g], e = gstart[g+1];
  int len = e - s;
  int i0 = s + (int)((long long)len * ch / POOL_CH);
  int i1 = s + (int)((long long)len * (ch+1) / POOL_CH);
  float inv = 1.f/(float)(len > 0 ? len : 1);
  float a = ga[f];
  float m = S1[g*128+f]*inv, ex2 = S2[g*128+f]*inv;
  float am = a*m;
  float rs = rsqrtf(ex2 - (2.f*a - a*a)*m*m + EPSV);
  float wv = gw[f], bv = gb[f];
  float a1 = 0.f;
  for(int n=i0; n<i1; n++){
    float v = b2f(x[(size_t)n*128 + f]);
    v = wv*(v-am)*rs + bv;
    a1 += fmaxf(v, 0.f);
  }
  if(i1 > i0) atomicAdd(&pooled[g*128+f], a1);
  __threadfence();                       // release: pooled adds visible device-wide
  __syncthreads();
  __shared__ int lastflag;
  if(f == 0)
    lastflag = (atomicAdd(&done[g], 1) == POOL_CH - 1);
  __syncthreads();
  if(!lastflag) return;
  __threadfence();                       // acquire: see all other blocks' pooled adds
  __shared__ float lg[NC];
  __shared__ float lse_s;
  if(f < NC){
    float acc = lb[f];
    for(int k=0; k<128; k++) acc += pooled[g*128+k]*inv*lw[k*NC + f];
    lg[f] = acc;
  }
  __syncthreads();
  if(f == 0){
    float mx = -1e30f;
    for(int c=0;c<NC;c++) mx = fmaxf(mx, lg[c]);
    float sm = 0.f;
    for(int c=0;c<NC;c++) sm += expf(lg[c]-mx);
    lse_s = mx + logf(sm);
  }
  __syncthreads();
  if(f < NC) out[g*NC + f] = lg[f] - lse_s;
}

// ---------------- launch (13 dispatches) ----------------
extern "C" void kernel_launch(void* const* d_in, const int* in_sizes, int n_in,
                              void* d_out, int out_size, void* d_ws, size_t ws_size,
                              hipStream_t stream)
{
  const float* x    = (const float*)d_in[0];
  const int*   ei   = (const int*)d_in[1];
  const int*   batch= (const int*)d_in[2];
  const float* w1   = (const float*)d_in[3];
  const float* b1   = (const float*)d_in[4];
  const float* w2   = (const float*)d_in[5];
  const float* b2   = (const float*)d_in[6];
  const float* w3   = (const float*)d_in[7];
  const float* b3   = (const float*)d_in[8];
  const float* g1w  = (const float*)d_in[9];
  const float* g1b  = (const float*)d_in[10];
  const float* g1a  = (const float*)d_in[11];
  const float* g2w  = (const float*)d_in[12];
  const float* g2b  = (const float*)d_in[13];
  const float* g2a  = (const float*)d_in[14];
  const float* g3w  = (const float*)d_in[15];
  const float* g3b  = (const float*)d_in[16];
  const float* g3a  = (const float*)d_in[17];
  const float* lw   = (const float*)d_in[18];
  const float* lb   = (const float*)d_in[19];
  float* out = (float*)d_out;

  char* p = (char*)d_ws;
  auto take = [&](size_t nbytes){ char* q = p; p += (nbytes + 255) & ~(size_t)255; return q; };
  ushort* gbuf    = (ushort*)take((size_t)NN*HD*2);
  ushort* bufB    = (ushort*)take((size_t)NN*HD*2);
  ushort* wT      = (ushort*)take((size_t)3*HD*HD*2);
  unsigned* ebuf  = (unsigned*)take((size_t)NBKT*BCAP*4);
  int*   srcs     = (int*)  take((size_t)NE*4);
  int*   rowstart = (int*)  take((size_t)(NN+1)*4);
  float* dinv     = (float*)take((size_t)NN*4);
  int*   cursor0  = (int*)  take((size_t)NBKT*4);
  int*   done     = (int*)  take((size_t)NG*4);
  int*   gstart   = (int*)  take((size_t)(NG+1)*4);
  float* Sbase    = (float*)take((size_t)(3*2*NG*HD + NG*HD)*4);  // 3x(S1,S2) + pooled
  if((size_t)(p - (char*)d_ws) > ws_size) return;  // workspace too small: fail visibly

  float* SL1  = Sbase;
  float* SL1b = Sbase + 1*NG*HD;
  float* SL2  = Sbase + 2*NG*HD;
  float* SL2b = Sbase + 3*NG*HD;
  float* SL3  = Sbase + 4*NG*HD;
  float* SL3b = Sbase + 5*NG*HD;
  float* pooled = Sbase + 6*NG*HD;

  k_init <<<409, 256, 0, stream>>>(batch, gstart, w1, w2, w3, wT, cursor0, done, rowstart, Sbase);
  k_bin  <<<BIN_BLOCKS, 256, 0, stream>>>(ei, cursor0, ebuf);
  k_sort <<<NBKT, 256, 0, stream>>>(ebuf, cursor0, srcs, rowstart, dinv);

  const int GB = (NN + 127)/128;     // 782
  const int AB = NN/8;               // 12500

  // ---- layer 1 ----
  k_gemm<0><<<GB, 256, 0, stream>>>(x, wT, gbuf, dinv, batch,
                                    nullptr, nullptr, nullptr, nullptr, nullptr, gstart);
  k_agg<<<AB, 256, 0, stream>>>(gbuf, rowstart, srcs, dinv, b1, bufB);
  k_stats<<<dim3(NG, STAT_CH), 128, 0, stream>>>(bufB, gstart, SL1, SL1b);

  // ---- layer 2 ----
  k_gemm<1><<<GB, 256, 0, stream>>>(bufB, wT + 16384, gbuf, dinv, batch,
                                    g1w, g1b, g1a, SL1, SL1b, gstart);
  k_agg<<<AB, 256, 0, stream>>>(gbuf, rowstart, srcs, dinv, b2, bufB);
  k_stats<<<dim3(NG, STAT_CH), 128, 0, stream>>>(bufB, gstart, SL2, SL2b);

  // ---- layer 3 ----
  k_gemm<1><<<GB, 256, 0, stream>>>(bufB, wT + 32768, gbuf, dinv, batch,
                                    g2w, g2b, g2a, SL2, SL2b, gstart);
  k_agg<<<AB, 256, 0, stream>>>(gbuf, rowstart, srcs, dinv, b3, bufB);
  k_stats<<<dim3(NG, STAT_CH), 128, 0, stream>>>(bufB, gstart, SL3, SL3b);

  // ---- pool + head (last-done block per graph computes head) ----
  k_poolhead<<<dim3(NG, POOL_CH), 128, 0, stream>>>(bufB, gstart, g3w, g3b, g3a,
                                                    SL3, SL3b, pooled, done, lw, lb, out);
}

// Round 11
// 422.719 us; speedup vs baseline: 3.0369x; 1.1422x over previous
//
#include <hip/hip_runtime.h>

#define NN 100000
#define NE 1600000
#define HD 128
#define NG 128
#define NC 10
#define EPSV 1e-5f

#define BSH 9                      // 512 dst nodes per bucket
#define NBKT ((NN + 511) >> 9)     // 196
#define BCAP 9216                  // slots per bucket region (mean 8192, sigma~90 -> +11 sigma)
#define BIN_BLOCKS ((NE + 4095) / 4096)  // 391
#define STAT_CH 8
#define POOL_CH 16

typedef __attribute__((ext_vector_type(8))) short short8;
typedef __attribute__((ext_vector_type(4))) float f32x4;

__device__ __forceinline__ float b2f(ushort u){ return __uint_as_float(((unsigned)u)<<16); }
__device__ __forceinline__ ushort f2b(float f){
  unsigned u = __float_as_uint(f);
  unsigned r = (u + 0x7FFFu + ((u>>16)&1u)) >> 16;   // RNE
  return (ushort)r;
}

// ---------------- init: granges + weight-prep + zeroing (S, cursor0) ----------------
// blocks 0..390: granges | 391..393: wT | 394..407: zero S+pooled | 408: cursor0/rowstart[NN]
__global__ __launch_bounds__(256)
void k_init(const int* __restrict__ batch, int* __restrict__ gstart,
            const float* __restrict__ w1, const float* __restrict__ w2,
            const float* __restrict__ w3, ushort* __restrict__ wT,
            int* __restrict__ cursor0, int* __restrict__ rowstart,
            float* __restrict__ zero_base)
{
  int b = blockIdx.x, t = threadIdx.x;
  if(b < 391){                       // granges: batch sorted -> contiguous segments
    int n = b*256 + t;
    if(n >= NN) return;
    int bb = batch[n];
    if(n == 0){
      for(int g=0; g<=bb; g++) gstart[g] = 0;
      int last = batch[NN-1];
      for(int g=last+1; g<=NG; g++) gstart[g] = NN;
    } else {
      int bp = batch[n-1];
      for(int g=bp+1; g<=bb; g++) gstart[g] = n;
    }
  } else if(b < 394){                // wT[layer][h][k] = bf16(w[k][h])
    const float* w = (b == 391) ? w1 : (b == 392) ? w2 : w3;
    ushort* o = wT + (b-391)*16384;
    #pragma unroll 4
    for(int i=0;i<64;i++){
      int e = i*256 + t;
      o[(e & 127)*128 + (e >> 7)] = f2b(w[e]);
    }
  } else if(b < 408){                // zero 3x(S1,S2)+pooled = 114688 floats
    #pragma unroll 8
    for(int i=0;i<32;i++) zero_base[(size_t)(b-394)*8192 + i*256 + t] = 0.f;
  } else {
    if(t < NBKT) cursor0[t] = 0;
    if(t == 0)   rowstart[NN] = NE;
  }
}

// ---------------- bin: edges -> per-bucket regions (LDS-staged, contiguous writes) ----------
// record = (dst_local:9 << 17) | src:17 ; region b occupies ebuf[b*BCAP ...]
__global__ __launch_bounds__(256) void k_bin(const int* __restrict__ ei, int* __restrict__ cursor0,
                                             unsigned* __restrict__ ebuf){
  __shared__ unsigned eb[4096];
  __shared__ unsigned char bb4[4096];
  __shared__ int hist[NBKT], lstart[NBKT], lcur[NBKT], rbase[NBKT];
  __shared__ int scanbuf[256];
  int t = threadIdx.x;
  if(t < NBKT) hist[t] = 0;
  __syncthreads();
  int base = blockIdx.x*4096;
  int nv = NE - base; if(nv > 4096) nv = 4096;
  int se[16], de[16];
  #pragma unroll
  for(int i=0;i<16;i++){
    int e = base + i*256 + t;
    if(e < NE){ se[i] = ei[e]; de[i] = ei[NE + e]; atomicAdd(&hist[de[i] >> BSH], 1); }
  }
  __syncthreads();
  int v = (t < NBKT) ? hist[t] : 0;
  scanbuf[t] = v; __syncthreads();
  for(int off=1; off<256; off<<=1){
    int y = scanbuf[t]; int z = (t>=off)?scanbuf[t-off]:0;
    __syncthreads(); scanbuf[t] = y+z; __syncthreads();
  }
  if(t < NBKT){
    int excl = (t>0)?scanbuf[t-1]:0;
    lstart[t] = excl; lcur[t] = excl;
    if(hist[t]) rbase[t] = t*BCAP + atomicAdd(&cursor0[t], hist[t]);
  }
  __syncthreads();
  #pragma unroll
  for(int i=0;i<16;i++){
    int e = base + i*256 + t;
    if(e < NE){
      int b = de[i] >> BSH;
      int idx = atomicAdd(&lcur[b], 1);
      eb[idx] = ((unsigned)(de[i] & 511) << 17) | (unsigned)se[i];
      bb4[idx] = (unsigned char)b;
    }
  }
  __syncthreads();
  #pragma unroll
  for(int i=0;i<16;i++){
    int slot = i*256 + t;
    if(slot < nv){
      int b = bb4[slot];
      ebuf[rbase[b] + (slot - lstart[b])] = eb[slot];
    }
  }
}

// ---------------- sort: per-bucket counting sort -> contiguous CSR (rowstart, srcs, dinv) ----
__global__ __launch_bounds__(256) void k_sort(const unsigned* __restrict__ ebuf,
                                              const int* __restrict__ cursor0,
                                              int* __restrict__ srcs, int* __restrict__ rowstart,
                                              float* __restrict__ dinv){
  __shared__ int hist[512], cur[512];
  __shared__ int scanbuf[256];
  int b = blockIdx.x, t = threadIdx.x;
  // contiguous base for this bucket = exclusive prefix of final counts
  int v = (t < NBKT) ? cursor0[t] : 0;
  scanbuf[t] = v; __syncthreads();
  for(int off=1; off<256; off<<=1){
    int y = scanbuf[t]; int z = (t>=off)?scanbuf[t-off]:0;
    __syncthreads(); scanbuf[t] = y+z; __syncthreads();
  }
  const int e0 = (b>0) ? scanbuf[b-1] : 0;
  const int cnt = cursor0[b];
  const unsigned* reg = ebuf + (size_t)b*BCAP;
  hist[t] = 0; hist[t+256] = 0;
  __syncthreads();
  for(int i = t; i < cnt; i += 256)
    atomicAdd(&hist[reg[i] >> 17], 1);
  __syncthreads();
  int s0 = hist[2*t], s1 = hist[2*t+1];
  scanbuf[t] = s0 + s1; __syncthreads();
  for(int off=1; off<256; off<<=1){
    int y = scanbuf[t]; int z = (t>=off)?scanbuf[t-off]:0;
    __syncthreads(); scanbuf[t] = y+z; __syncthreads();
  }
  int excl = (t>0)?scanbuf[t-1]:0;
  cur[2*t] = excl; cur[2*t+1] = excl + s0;
  int d0 = (b << BSH) + 2*t, d1 = d0 + 1;
  if(d0 < NN){ rowstart[d0] = e0 + excl;      dinv[d0] = rsqrtf((float)(s0 + 1)); }
  if(d1 < NN){ rowstart[d1] = e0 + excl + s0; dinv[d1] = rsqrtf((float)(s1 + 1)); }
  __syncthreads();
  for(int i = t; i < cnt; i += 256){
    unsigned pk = reg[i];
    int dl = pk >> 17;
    int pos = e0 + atomicAdd(&cur[dl], 1);
    srcs[pos] = (int)(pk & 0x1FFFFu);
  }
}

// ---------------- MFMA GEMM: g[node][h] = bf16( dinv[node] * (norm_relu(in[node]) @ w)[h] ) ----
// NORM=0: raw fp32 input (layer 1). NORM=1: bf16 input + GraphNorm (inline from S1/S2) + ReLU.
template<int NORM>
__global__ __launch_bounds__(256)
void k_gemm(const void* __restrict__ in_, const ushort* __restrict__ wT,
            ushort* __restrict__ g, const float* __restrict__ dinv,
            const int* __restrict__ batch,
            const float* __restrict__ gw, const float* __restrict__ gb,
            const float* __restrict__ ga, const float* __restrict__ S1,
            const float* __restrict__ S2, const int* __restrict__ gstart)
{
  __shared__ ushort lds_a[128*136];
  __shared__ float sdinv[128];
  const int t = threadIdx.x;
  const int row0 = blockIdx.x * 128;
  {
    const int l = t & 31;
    const int rr = t >> 5;
    if(t < 128){
      int node = row0 + t;
      sdinv[t] = (node < NN) ? dinv[node] : 0.f;
    }
    float4 gwv, gbv, gav;
    float4 amv = make_float4(0.f,0.f,0.f,0.f), rsv = make_float4(0.f,0.f,0.f,0.f);
    int gprev = -1;
    if(NORM){
      gwv = ((const float4*)gw)[l]; gbv = ((const float4*)gb)[l];
      gav = ((const float4*)ga)[l];
    }
    #pragma unroll 4
    for(int rb = 0; rb < 16; rb++){
      int r = rb*8 + rr;
      int node = row0 + r;
      float4 v = make_float4(0.f,0.f,0.f,0.f);
      if(node < NN){
        if(NORM){
          ushort4 raw = ((const ushort4*)in_)[(size_t)node*32 + l];
          v = make_float4(b2f(raw.x), b2f(raw.y), b2f(raw.z), b2f(raw.w));
          int gg = batch[node];
          if(gg != gprev){
            gprev = gg;
            int c0 = gstart[gg], c1 = gstart[gg+1];
            float inv = 1.f/(float)((c1-c0) > 0 ? (c1-c0) : 1);
            float4 s1v = ((const float4*)S1)[gg*32 + l];
            float4 s2v = ((const float4*)S2)[gg*32 + l];
            float m, ex2, a;
            m = s1v.x*inv; ex2 = s2v.x*inv; a = gav.x;
            amv.x = a*m; rsv.x = rsqrtf(ex2 - (2.f*a - a*a)*m*m + EPSV);
            m = s1v.y*inv; ex2 = s2v.y*inv; a = gav.y;
            amv.y = a*m; rsv.y = rsqrtf(ex2 - (2.f*a - a*a)*m*m + EPSV);
            m = s1v.z*inv; ex2 = s2v.z*inv; a = gav.z;
            amv.z = a*m; rsv.z = rsqrtf(ex2 - (2.f*a - a*a)*m*m + EPSV);
            m = s1v.w*inv; ex2 = s2v.w*inv; a = gav.w;
            amv.w = a*m; rsv.w = rsqrtf(ex2 - (2.f*a - a*a)*m*m + EPSV);
          }
          v.x = fmaxf(gwv.x*(v.x-amv.x)*rsv.x + gbv.x, 0.f);
          v.y = fmaxf(gwv.y*(v.y-amv.y)*rsv.y + gbv.y, 0.f);
          v.z = fmaxf(gwv.z*(v.z-amv.z)*rsv.z + gbv.z, 0.f);
          v.w = fmaxf(gwv.w*(v.w-amv.w)*rsv.w + gbv.w, 0.f);
        } else {
          v = ((const float4*)in_)[(size_t)node*32 + l];
        }
      }
      ushort4 b4;
      b4.x = f2b(v.x); b4.y = f2b(v.y); b4.z = f2b(v.z); b4.w = f2b(v.w);
      *(ushort4*)(lds_a + r*136 + l*4) = b4;
    }
  }
  __syncthreads();

  const int wv = t >> 6, l = t & 63, lc = l & 15, lk = l >> 4;
  short8 bfrag[2][4];
  #pragma unroll
  for(int tt=0; tt<2; tt++){
    int col = wv*32 + tt*16 + lc;
    #pragma unroll
    for(int s=0; s<4; s++)
      bfrag[tt][s] = *(const short8*)(wT + col*128 + s*32 + lk*8);
  }
  f32x4 acc[8][2];
  #pragma unroll
  for(int m=0;m<8;m++){ acc[m][0] = (f32x4)0.f; acc[m][1] = (f32x4)0.f; }
  #pragma unroll
  for(int m=0; m<8; m++){
    const ushort* ap = lds_a + (m*16 + lc)*136 + lk*8;
    #pragma unroll
    for(int s=0; s<4; s++){
      short8 a = *(const short8*)(ap + s*32);
      acc[m][0] = __builtin_amdgcn_mfma_f32_16x16x32_bf16(a, bfrag[0][s], acc[m][0], 0, 0, 0);
      acc[m][1] = __builtin_amdgcn_mfma_f32_16x16x32_bf16(a, bfrag[1][s], acc[m][1], 0, 0, 0);
    }
  }
  #pragma unroll
  for(int m=0; m<8; m++){
    #pragma unroll
    for(int tt=0; tt<2; tt++){
      int colg = wv*32 + tt*16 + lc;
      #pragma unroll
      for(int r=0; r<4; r++){
        int row = m*16 + lk*4 + r;
        int node = row0 + row;
        if(node < NN)
          g[(size_t)node*128 + colg] = f2b(acc[m][tt][r] * sdinv[row]);
      }
    }
  }
}

// ---------------- lean aggregation over dst-sorted edges (bf16 gather + bf16 out) ----------
__global__ __launch_bounds__(256)
void k_agg(const ushort* __restrict__ g, const int* __restrict__ rowstart,
           const int* __restrict__ srcs, const float* __restrict__ dinv,
           const float* __restrict__ bias, ushort* __restrict__ outp)
{
  const int lane = threadIdx.x & 31;
  const int node = blockIdx.x*8 + (threadIdx.x >> 5);
  const int e0 = rowstart[node], e1 = rowstart[node+1];
  float ax=0.f, ay=0.f, az=0.f, aw=0.f;
  float bx=0.f, by=0.f, bz=0.f, bw=0.f;
  const ushort4* gp = (const ushort4*)g;
  int e = e0;
  for(; e+7 < e1; e += 8){
    int si[8];
    #pragma unroll
    for(int i=0;i<8;i++) si[i] = srcs[e+i];
    ushort4 v[8];
    #pragma unroll
    for(int i=0;i<8;i++) v[i] = gp[(size_t)si[i]*32 + lane];
    #pragma unroll
    for(int i=0;i<8;i++){
      if(i&1){ bx += b2f(v[i].x); by += b2f(v[i].y); bz += b2f(v[i].z); bw += b2f(v[i].w); }
      else   { ax += b2f(v[i].x); ay += b2f(v[i].y); az += b2f(v[i].z); aw += b2f(v[i].w); }
    }
  }
  for(; e+3 < e1; e += 4){
    int si[4];
    #pragma unroll
    for(int i=0;i<4;i++) si[i] = srcs[e+i];
    ushort4 v[4];
    #pragma unroll
    for(int i=0;i<4;i++) v[i] = gp[(size_t)si[i]*32 + lane];
    #pragma unroll
    for(int i=0;i<4;i++){
      if(i&1){ bx += b2f(v[i].x); by += b2f(v[i].y); bz += b2f(v[i].z); bw += b2f(v[i].w); }
      else   { ax += b2f(v[i].x); ay += b2f(v[i].y); az += b2f(v[i].z); aw += b2f(v[i].w); }
    }
  }
  for(; e < e1; e++){
    ushort4 v = gp[(size_t)srcs[e]*32 + lane];
    ax += b2f(v.x); ay += b2f(v.y); az += b2f(v.z); aw += b2f(v.w);
  }
  ushort4 vs = gp[(size_t)node*32 + lane];
  float dv = dinv[node];
  float4 bv = ((const float4*)bias)[lane];
  ushort4 o4;
  o4.x = f2b(dv*(ax+bx+b2f(vs.x))+bv.x);
  o4.y = f2b(dv*(ay+by+b2f(vs.y))+bv.y);
  o4.z = f2b(dv*(az+bz+b2f(vs.z))+bv.z);
  o4.w = f2b(dv*(aw+bw+b2f(vs.w))+bv.w);
  ((ushort4*)outp)[(size_t)node*32 + lane] = o4;
}

// ---------------- per-graph moments from bf16 (one pass: sum x, sum x^2) ----------------
__global__ __launch_bounds__(128)
void k_stats(const ushort* __restrict__ x, const int* __restrict__ gstart,
             float* __restrict__ S1, float* __restrict__ S2)
{
  int g = blockIdx.x, ch = blockIdx.y, f = threadIdx.x;
  int s = gstart[g], e = gstart[g+1];
  int len = e - s;
  int i0 = s + (int)((long long)len * ch / STAT_CH);
  int i1 = s + (int)((long long)len * (ch+1) / STAT_CH);
  float a1 = 0.f, a2 = 0.f;
  for(int n=i0; n<i1; n++){
    float v = b2f(x[(size_t)n*128 + f]);
    a1 += v; a2 += v*v;
  }
  if(i1 > i0){
    atomicAdd(&S1[g*128+f], a1);
    atomicAdd(&S2[g*128+f], a2);
  }
}

// ---------------- pooled[g][f] += sum_n relu(norm(x[n][f]))  (norm inline from S1/S2) ------
__global__ __launch_bounds__(128)
void k_pool(const ushort* __restrict__ x, const int* __restrict__ gstart,
            const float* __restrict__ gw, const float* __restrict__ gb,
            const float* __restrict__ ga, const float* __restrict__ S1,
            const float* __restrict__ S2, float* __restrict__ pooled)
{
  int g = blockIdx.x, ch = blockIdx.y, f = threadIdx.x;
  int s = gstart[g], e = gstart[g+1];
  int len = e - s;
  int i0 = s + (int)((long long)len * ch / POOL_CH);
  int i1 = s + (int)((long long)len * (ch+1) / POOL_CH);
  float inv = 1.f/(float)(len > 0 ? len : 1);
  float a = ga[f];
  float m = S1[g*128+f]*inv, ex2 = S2[g*128+f]*inv;
  float am = a*m;
  float rs = rsqrtf(ex2 - (2.f*a - a*a)*m*m + EPSV);
  float wv = gw[f], bv = gb[f];
  float a1 = 0.f;
  for(int n=i0; n<i1; n++){
    float v = b2f(x[(size_t)n*128 + f]);
    v = wv*(v-am)*rs + bv;
    a1 += fmaxf(v, 0.f);
  }
  if(i1 > i0) atomicAdd(&pooled[g*128+f], a1);
}

// ---------------- head: logits = pooled/cnt @ lw + lb, log_softmax ----------------
__global__ __launch_bounds__(64)
void k_head(const float* __restrict__ pooled, const int* __restrict__ gstart,
            const float* __restrict__ lw, const float* __restrict__ lb,
            float* __restrict__ out)
{
  int g = blockIdx.x, t = threadIdx.x;
  __shared__ float lg[NC];
  __shared__ float lse_s;
  int len = gstart[g+1] - gstart[g];
  float inv = 1.f/(float)(len > 0 ? len : 1);
  if(t < NC){
    float acc = lb[t];
    for(int f=0; f<128; f++) acc += pooled[g*128+f]*inv*lw[f*NC + t];
    lg[t] = acc;
  }
  __syncthreads();
  if(t == 0){
    float mx = -1e30f;
    for(int c=0;c<NC;c++) mx = fmaxf(mx, lg[c]);
    float sm = 0.f;
    for(int c=0;c<NC;c++) sm += expf(lg[c]-mx);
    lse_s = mx + logf(sm);
  }
  __syncthreads();
  if(t < NC) out[g*NC + t] = lg[t] - lse_s;
}

// ---------------- launch (14 dispatches) ----------------
extern "C" void kernel_launch(void* const* d_in, const int* in_sizes, int n_in,
                              void* d_out, int out_size, void* d_ws, size_t ws_size,
                              hipStream_t stream)
{
  const float* x    = (const float*)d_in[0];
  const int*   ei   = (const int*)d_in[1];
  const int*   batch= (const int*)d_in[2];
  const float* w1   = (const float*)d_in[3];
  const float* b1   = (const float*)d_in[4];
  const float* w2   = (const float*)d_in[5];
  const float* b2   = (const float*)d_in[6];
  const float* w3   = (const float*)d_in[7];
  const float* b3   = (const float*)d_in[8];
  const float* g1w  = (const float*)d_in[9];
  const float* g1b  = (const float*)d_in[10];
  const float* g1a  = (const float*)d_in[11];
  const float* g2w  = (const float*)d_in[12];
  const float* g2b  = (const float*)d_in[13];
  const float* g2a  = (const float*)d_in[14];
  const float* g3w  = (const float*)d_in[15];
  const float* g3b  = (const float*)d_in[16];
  const float* g3a  = (const float*)d_in[17];
  const float* lw   = (const float*)d_in[18];
  const float* lb   = (const float*)d_in[19];
  float* out = (float*)d_out;

  char* p = (char*)d_ws;
  auto take = [&](size_t nbytes){ char* q = p; p += (nbytes + 255) & ~(size_t)255; return q; };
  ushort* gbuf    = (ushort*)take((size_t)NN*HD*2);
  ushort* bufB    = (ushort*)take((size_t)NN*HD*2);
  ushort* wT      = (ushort*)take((size_t)3*HD*HD*2);
  unsigned* ebuf  = (unsigned*)take((size_t)NBKT*BCAP*4);
  int*   srcs     = (int*)  take((size_t)NE*4);
  int*   rowstart = (int*)  take((size_t)(NN+1)*4);
  float* dinv     = (float*)take((size_t)NN*4);
  int*   cursor0  = (int*)  take((size_t)NBKT*4);
  int*   gstart   = (int*)  take((size_t)(NG+1)*4);
  float* Sbase    = (float*)take((size_t)(3*2*NG*HD + NG*HD)*4);  // 3x(S1,S2) + pooled
  if((size_t)(p - (char*)d_ws) > ws_size) return;  // workspace too small: fail visibly

  float* SL1  = Sbase;
  float* SL1b = Sbase + 1*NG*HD;
  float* SL2  = Sbase + 2*NG*HD;
  float* SL2b = Sbase + 3*NG*HD;
  float* SL3  = Sbase + 4*NG*HD;
  float* SL3b = Sbase + 5*NG*HD;
  float* pooled = Sbase + 6*NG*HD;

  k_init <<<409, 256, 0, stream>>>(batch, gstart, w1, w2, w3, wT, cursor0, rowstart, Sbase);
  k_bin  <<<BIN_BLOCKS, 256, 0, stream>>>(ei, cursor0, ebuf);
  k_sort <<<NBKT, 256, 0, stream>>>(ebuf, cursor0, srcs, rowstart, dinv);

  const int GB = (NN + 127)/128;     // 782
  const int AB = NN/8;               // 12500

  // ---- layer 1 ----
  k_gemm<0><<<GB, 256, 0, stream>>>(x, wT, gbuf, dinv, batch,
                                    nullptr, nullptr, nullptr, nullptr, nullptr, gstart);
  k_agg<<<AB, 256, 0, stream>>>(gbuf, rowstart, srcs, dinv, b1, bufB);
  k_stats<<<dim3(NG, STAT_CH), 128, 0, stream>>>(bufB, gstart, SL1, SL1b);

  // ---- layer 2 ----
  k_gemm<1><<<GB, 256, 0, stream>>>(bufB, wT + 16384, gbuf, dinv, batch,
                                    g1w, g1b, g1a, SL1, SL1b, gstart);
  k_agg<<<AB, 256, 0, stream>>>(gbuf, rowstart, srcs, dinv, b2, bufB);
  k_stats<<<dim3(NG, STAT_CH), 128, 0, stream>>>(bufB, gstart, SL2, SL2b);

  // ---- layer 3 ----
  k_gemm<1><<<GB, 256, 0, stream>>>(bufB, wT + 32768, gbuf, dinv, batch,
                                    g2w, g2b, g2a, SL2, SL2b, gstart);
  k_agg<<<AB, 256, 0, stream>>>(gbuf, rowstart, srcs, dinv, b3, bufB);
  k_stats<<<dim3(NG, STAT_CH), 128, 0, stream>>>(bufB, gstart, SL3, SL3b);

  // ---- pool + head ----
  k_pool<<<dim3(NG, POOL_CH), 128, 0, stream>>>(bufB, gstart, g3w, g3b, g3a, SL3, SL3b, pooled);
  k_head<<<NG, 64, 0, stream>>>(pooled, gstart, lw, lb, out);
}

// Round 12
// 418.213 us; speedup vs baseline: 3.0696x; 1.0108x over previous
//
#include <hip/hip_runtime.h>

#define NN 100000
#define NE 1600000
#define HD 128
#define NG 128
#define NC 10
#define EPSV 1e-5f

#define BSH 9                      // 512 dst nodes per bucket
#define NBKT ((NN + 511) >> 9)     // 196
#define BCAP 9216                  // slots per bucket region (mean 8192, sigma~90 -> +11 sigma)
#define BIN_BLOCKS ((NE + 4095) / 4096)  // 391
#define STAT_CH 8
#define POOL_CH 16

typedef __attribute__((ext_vector_type(8))) short short8;
typedef __attribute__((ext_vector_type(4))) float f32x4;

__device__ __forceinline__ float b2f(ushort u){ return __uint_as_float(((unsigned)u)<<16); }
__device__ __forceinline__ ushort f2b(float f){
  unsigned u = __float_as_uint(f);
  unsigned r = (u + 0x7FFFu + ((u>>16)&1u)) >> 16;   // RNE
  return (ushort)r;
}

// ---------------- init: granges + weight-prep + zeroing (S, cursor0) ----------------
__global__ __launch_bounds__(256)
void k_init(const int* __restrict__ batch, int* __restrict__ gstart,
            const float* __restrict__ w1, const float* __restrict__ w2,
            const float* __restrict__ w3, ushort* __restrict__ wT,
            int* __restrict__ cursor0, int* __restrict__ rowstart,
            float* __restrict__ zero_base)
{
  int b = blockIdx.x, t = threadIdx.x;
  if(b < 391){                       // granges: batch sorted -> contiguous segments
    int n = b*256 + t;
    if(n >= NN) return;
    int bb = batch[n];
    if(n == 0){
      for(int g=0; g<=bb; g++) gstart[g] = 0;
      int last = batch[NN-1];
      for(int g=last+1; g<=NG; g++) gstart[g] = NN;
    } else {
      int bp = batch[n-1];
      for(int g=bp+1; g<=bb; g++) gstart[g] = n;
    }
  } else if(b < 394){                // wT[layer][h][k] = bf16(w[k][h])
    const float* w = (b == 391) ? w1 : (b == 392) ? w2 : w3;
    ushort* o = wT + (b-391)*16384;
    #pragma unroll 4
    for(int i=0;i<64;i++){
      int e = i*256 + t;
      o[(e & 127)*128 + (e >> 7)] = f2b(w[e]);
    }
  } else if(b < 408){                // zero 3x(S1,S2)+pooled = 114688 floats
    #pragma unroll 8
    for(int i=0;i<32;i++) zero_base[(size_t)(b-394)*8192 + i*256 + t] = 0.f;
  } else {
    if(t < NBKT) cursor0[t] = 0;
    if(t == 0)   rowstart[NN] = NE;
  }
}

// ---------------- bin: edges -> per-bucket regions (LDS-staged, contiguous writes) ----------
__global__ __launch_bounds__(256) void k_bin(const int* __restrict__ ei, int* __restrict__ cursor0,
                                             unsigned* __restrict__ ebuf){
  __shared__ unsigned eb[4096];
  __shared__ unsigned char bb4[4096];
  __shared__ int hist[NBKT], lstart[NBKT], lcur[NBKT], rbase[NBKT];
  __shared__ int scanbuf[256];
  int t = threadIdx.x;
  if(t < NBKT) hist[t] = 0;
  __syncthreads();
  int base = blockIdx.x*4096;
  int nv = NE - base; if(nv > 4096) nv = 4096;
  int se[16], de[16];
  #pragma unroll
  for(int i=0;i<16;i++){
    int e = base + i*256 + t;
    if(e < NE){ se[i] = ei[e]; de[i] = ei[NE + e]; atomicAdd(&hist[de[i] >> BSH], 1); }
  }
  __syncthreads();
  int v = (t < NBKT) ? hist[t] : 0;
  scanbuf[t] = v; __syncthreads();
  for(int off=1; off<256; off<<=1){
    int y = scanbuf[t]; int z = (t>=off)?scanbuf[t-off]:0;
    __syncthreads(); scanbuf[t] = y+z; __syncthreads();
  }
  if(t < NBKT){
    int excl = (t>0)?scanbuf[t-1]:0;
    lstart[t] = excl; lcur[t] = excl;
    if(hist[t]) rbase[t] = t*BCAP + atomicAdd(&cursor0[t], hist[t]);
  }
  __syncthreads();
  #pragma unroll
  for(int i=0;i<16;i++){
    int e = base + i*256 + t;
    if(e < NE){
      int b = de[i] >> BSH;
      int idx = atomicAdd(&lcur[b], 1);
      eb[idx] = ((unsigned)(de[i] & 511) << 17) | (unsigned)se[i];
      bb4[idx] = (unsigned char)b;
    }
  }
  __syncthreads();
  #pragma unroll
  for(int i=0;i<16;i++){
    int slot = i*256 + t;
    if(slot < nv){
      int b = bb4[slot];
      ebuf[rbase[b] + (slot - lstart[b])] = eb[slot];
    }
  }
}

// ---------------- sort: per-bucket counting sort -> contiguous CSR (rowstart, srcs, dinv) ----
__global__ __launch_bounds__(256) void k_sort(const unsigned* __restrict__ ebuf,
                                              const int* __restrict__ cursor0,
                                              int* __restrict__ srcs, int* __restrict__ rowstart,
                                              float* __restrict__ dinv){
  __shared__ int hist[512], cur[512];
  __shared__ int scanbuf[256];
  int b = blockIdx.x, t = threadIdx.x;
  int v = (t < NBKT) ? cursor0[t] : 0;
  scanbuf[t] = v; __syncthreads();
  for(int off=1; off<256; off<<=1){
    int y = scanbuf[t]; int z = (t>=off)?scanbuf[t-off]:0;
    __syncthreads(); scanbuf[t] = y+z; __syncthreads();
  }
  const int e0 = (b>0) ? scanbuf[b-1] : 0;
  const int cnt = cursor0[b];
  const unsigned* reg = ebuf + (size_t)b*BCAP;
  hist[t] = 0; hist[t+256] = 0;
  __syncthreads();
  for(int i = t; i < cnt; i += 256)
    atomicAdd(&hist[reg[i] >> 17], 1);
  __syncthreads();
  int s0 = hist[2*t], s1 = hist[2*t+1];
  scanbuf[t] = s0 + s1; __syncthreads();
  for(int off=1; off<256; off<<=1){
    int y = scanbuf[t]; int z = (t>=off)?scanbuf[t-off]:0;
    __syncthreads(); scanbuf[t] = y+z; __syncthreads();
  }
  int excl = (t>0)?scanbuf[t-1]:0;
  cur[2*t] = excl; cur[2*t+1] = excl + s0;
  int d0 = (b << BSH) + 2*t, d1 = d0 + 1;
  if(d0 < NN){ rowstart[d0] = e0 + excl;      dinv[d0] = rsqrtf((float)(s0 + 1)); }
  if(d1 < NN){ rowstart[d1] = e0 + excl + s0; dinv[d1] = rsqrtf((float)(s1 + 1)); }
  __syncthreads();
  for(int i = t; i < cnt; i += 256){
    unsigned pk = reg[i];
    int dl = pk >> 17;
    int pos = e0 + atomicAdd(&cur[dl], 1);
    srcs[pos] = (int)(pk & 0x1FFFFu);
  }
}

// ---------------- MFMA GEMM: g[node][h] = bf16( dinv[node] * (norm_relu(in[node]) @ w)[h] ) ----
// NORM=0: raw fp32 input (layer 1). NORM=1: bf16 input + GraphNorm (inline from S1/S2) + ReLU.
// Epilogue: acc -> LDS (bf16) -> coalesced ushort8 stores (16B/lane).
template<int NORM>
__global__ __launch_bounds__(256)
void k_gemm(const void* __restrict__ in_, const ushort* __restrict__ wT,
            ushort* __restrict__ g, const float* __restrict__ dinv,
            const int* __restrict__ batch,
            const float* __restrict__ gw, const float* __restrict__ gb,
            const float* __restrict__ ga, const float* __restrict__ S1,
            const float* __restrict__ S2, const int* __restrict__ gstart)
{
  __shared__ ushort lds_a[128*136];
  __shared__ float sdinv[128];
  const int t = threadIdx.x;
  const int row0 = blockIdx.x * 128;
  {
    const int l = t & 31;
    const int rr = t >> 5;
    if(t < 128){
      int node = row0 + t;
      sdinv[t] = (node < NN) ? dinv[node] : 0.f;
    }
    float4 gwv, gbv, gav;
    float4 amv = make_float4(0.f,0.f,0.f,0.f), rsv = make_float4(0.f,0.f,0.f,0.f);
    int gprev = -1;
    if(NORM){
      gwv = ((const float4*)gw)[l]; gbv = ((const float4*)gb)[l];
      gav = ((const float4*)ga)[l];
    }
    #pragma unroll 4
    for(int rb = 0; rb < 16; rb++){
      int r = rb*8 + rr;
      int node = row0 + r;
      float4 v = make_float4(0.f,0.f,0.f,0.f);
      if(node < NN){
        if(NORM){
          ushort4 raw = ((const ushort4*)in_)[(size_t)node*32 + l];
          v = make_float4(b2f(raw.x), b2f(raw.y), b2f(raw.z), b2f(raw.w));
          int gg = batch[node];
          if(gg != gprev){
            gprev = gg;
            int c0 = gstart[gg], c1 = gstart[gg+1];
            float inv = 1.f/(float)((c1-c0) > 0 ? (c1-c0) : 1);
            float4 s1v = ((const float4*)S1)[gg*32 + l];
            float4 s2v = ((const float4*)S2)[gg*32 + l];
            float m, ex2, a;
            m = s1v.x*inv; ex2 = s2v.x*inv; a = gav.x;
            amv.x = a*m; rsv.x = rsqrtf(ex2 - (2.f*a - a*a)*m*m + EPSV);
            m = s1v.y*inv; ex2 = s2v.y*inv; a = gav.y;
            amv.y = a*m; rsv.y = rsqrtf(ex2 - (2.f*a - a*a)*m*m + EPSV);
            m = s1v.z*inv; ex2 = s2v.z*inv; a = gav.z;
            amv.z = a*m; rsv.z = rsqrtf(ex2 - (2.f*a - a*a)*m*m + EPSV);
            m = s1v.w*inv; ex2 = s2v.w*inv; a = gav.w;
            amv.w = a*m; rsv.w = rsqrtf(ex2 - (2.f*a - a*a)*m*m + EPSV);
          }
          v.x = fmaxf(gwv.x*(v.x-amv.x)*rsv.x + gbv.x, 0.f);
          v.y = fmaxf(gwv.y*(v.y-amv.y)*rsv.y + gbv.y, 0.f);
          v.z = fmaxf(gwv.z*(v.z-amv.z)*rsv.z + gbv.z, 0.f);
          v.w = fmaxf(gwv.w*(v.w-amv.w)*rsv.w + gbv.w, 0.f);
        } else {
          v = ((const float4*)in_)[(size_t)node*32 + l];
        }
      }
      ushort4 b4;
      b4.x = f2b(v.x); b4.y = f2b(v.y); b4.z = f2b(v.z); b4.w = f2b(v.w);
      *(ushort4*)(lds_a + r*136 + l*4) = b4;
    }
  }
  __syncthreads();

  const int wv = t >> 6, l = t & 63, lc = l & 15, lk = l >> 4;
  short8 bfrag[2][4];
  #pragma unroll
  for(int tt=0; tt<2; tt++){
    int col = wv*32 + tt*16 + lc;
    #pragma unroll
    for(int s=0; s<4; s++)
      bfrag[tt][s] = *(const short8*)(wT + col*128 + s*32 + lk*8);
  }
  f32x4 acc[8][2];
  #pragma unroll
  for(int m=0;m<8;m++){ acc[m][0] = (f32x4)0.f; acc[m][1] = (f32x4)0.f; }
  #pragma unroll
  for(int m=0; m<8; m++){
    const ushort* ap = lds_a + (m*16 + lc)*136 + lk*8;
    #pragma unroll
    for(int s=0; s<4; s++){
      short8 a = *(const short8*)(ap + s*32);
      acc[m][0] = __builtin_amdgcn_mfma_f32_16x16x32_bf16(a, bfrag[0][s], acc[m][0], 0, 0, 0);
      acc[m][1] = __builtin_amdgcn_mfma_f32_16x16x32_bf16(a, bfrag[1][s], acc[m][1], 0, 0, 0);
    }
  }
  __syncthreads();     // MFMA reads of lds_a done; reuse as C staging tile

  // stage C into LDS as bf16 (scaled by dinv), then coalesced 16B stores
  #pragma unroll
  for(int m=0; m<8; m++){
    #pragma unroll
    for(int tt=0; tt<2; tt++){
      int colg = wv*32 + tt*16 + lc;
      #pragma unroll
      for(int r=0; r<4; r++){
        int row = m*16 + lk*4 + r;
        lds_a[row*136 + colg] = f2b(acc[m][tt][r] * sdinv[row]);
      }
    }
  }
  __syncthreads();
  {
    ushort* gout = g + (size_t)row0*128;
    int maxrow = NN - row0; if(maxrow > 128) maxrow = 128;
    #pragma unroll
    for(int i=0; i<8; i++){
      int idx = i*256 + t;           // 2048 ushort8-groups: row = idx>>4, grp = idx&15
      int row = idx >> 4, grp = idx & 15;
      if(row < maxrow){
        short8 c8 = *(const short8*)(lds_a + row*136 + grp*8);
        *(short8*)(gout + row*128 + grp*8) = c8;
      }
    }
  }
}

// ---------------- lean aggregation over dst-sorted edges (bf16 gather + bf16 out) ----------
__global__ __launch_bounds__(256)
void k_agg(const ushort* __restrict__ g, const int* __restrict__ rowstart,
           const int* __restrict__ srcs, const float* __restrict__ dinv,
           const float* __restrict__ bias, ushort* __restrict__ outp)
{
  const int lane = threadIdx.x & 31;
  const int node = blockIdx.x*8 + (threadIdx.x >> 5);
  const int e0 = rowstart[node], e1 = rowstart[node+1];
  float ax=0.f, ay=0.f, az=0.f, aw=0.f;
  float bx=0.f, by=0.f, bz=0.f, bw=0.f;
  const ushort4* gp = (const ushort4*)g;
  int e = e0;
  for(; e+7 < e1; e += 8){
    int si[8];
    #pragma unroll
    for(int i=0;i<8;i++) si[i] = srcs[e+i];
    ushort4 v[8];
    #pragma unroll
    for(int i=0;i<8;i++) v[i] = gp[(size_t)si[i]*32 + lane];
    #pragma unroll
    for(int i=0;i<8;i++){
      if(i&1){ bx += b2f(v[i].x); by += b2f(v[i].y); bz += b2f(v[i].z); bw += b2f(v[i].w); }
      else   { ax += b2f(v[i].x); ay += b2f(v[i].y); az += b2f(v[i].z); aw += b2f(v[i].w); }
    }
  }
  for(; e+3 < e1; e += 4){
    int si[4];
    #pragma unroll
    for(int i=0;i<4;i++) si[i] = srcs[e+i];
    ushort4 v[4];
    #pragma unroll
    for(int i=0;i<4;i++) v[i] = gp[(size_t)si[i]*32 + lane];
    #pragma unroll
    for(int i=0;i<4;i++){
      if(i&1){ bx += b2f(v[i].x); by += b2f(v[i].y); bz += b2f(v[i].z); bw += b2f(v[i].w); }
      else   { ax += b2f(v[i].x); ay += b2f(v[i].y); az += b2f(v[i].z); aw += b2f(v[i].w); }
    }
  }
  for(; e < e1; e++){
    ushort4 v = gp[(size_t)srcs[e]*32 + lane];
    ax += b2f(v.x); ay += b2f(v.y); az += b2f(v.z); aw += b2f(v.w);
  }
  ushort4 vs = gp[(size_t)node*32 + lane];
  float dv = dinv[node];
  float4 bv = ((const float4*)bias)[lane];
  ushort4 o4;
  o4.x = f2b(dv*(ax+bx+b2f(vs.x))+bv.x);
  o4.y = f2b(dv*(ay+by+b2f(vs.y))+bv.y);
  o4.z = f2b(dv*(az+bz+b2f(vs.z))+bv.z);
  o4.w = f2b(dv*(aw+bw+b2f(vs.w))+bv.w);
  ((ushort4*)outp)[(size_t)node*32 + lane] = o4;
}

// ---------------- per-graph moments from bf16 (one pass: sum x, sum x^2) ----------------
__global__ __launch_bounds__(128)
void k_stats(const ushort* __restrict__ x, const int* __restrict__ gstart,
             float* __restrict__ S1, float* __restrict__ S2)
{
  int g = blockIdx.x, ch = blockIdx.y, f = threadIdx.x;
  int s = gstart[g], e = gstart[g+1];
  int len = e - s;
  int i0 = s + (int)((long long)len * ch / STAT_CH);
  int i1 = s + (int)((long long)len * (ch+1) / STAT_CH);
  float a1 = 0.f, a2 = 0.f;
  for(int n=i0; n<i1; n++){
    float v = b2f(x[(size_t)n*128 + f]);
    a1 += v; a2 += v*v;
  }
  if(i1 > i0){
    atomicAdd(&S1[g*128+f], a1);
    atomicAdd(&S2[g*128+f], a2);
  }
}

// ---------------- pooled[g][f] += sum_n relu(norm(x[n][f]))  (norm inline from S1/S2) ------
__global__ __launch_bounds__(128)
void k_pool(const ushort* __restrict__ x, const int* __restrict__ gstart,
            const float* __restrict__ gw, const float* __restrict__ gb,
            const float* __restrict__ ga, const float* __restrict__ S1,
            const float* __restrict__ S2, float* __restrict__ pooled)
{
  int g = blockIdx.x, ch = blockIdx.y, f = threadIdx.x;
  int s = gstart[g], e = gstart[g+1];
  int len = e - s;
  int i0 = s + (int)((long long)len * ch / POOL_CH);
  int i1 = s + (int)((long long)len * (ch+1) / POOL_CH);
  float inv = 1.f/(float)(len > 0 ? len : 1);
  float a = ga[f];
  float m = S1[g*128+f]*inv, ex2 = S2[g*128+f]*inv;
  float am = a*m;
  float rs = rsqrtf(ex2 - (2.f*a - a*a)*m*m + EPSV);
  float wv = gw[f], bv = gb[f];
  float a1 = 0.f;
  for(int n=i0; n<i1; n++){
    float v = b2f(x[(size_t)n*128 + f]);
    v = wv*(v-am)*rs + bv;
    a1 += fmaxf(v, 0.f);
  }
  if(i1 > i0) atomicAdd(&pooled[g*128+f], a1);
}

// ---------------- head: logits = pooled/cnt @ lw + lb, log_softmax ----------------
__global__ __launch_bounds__(64)
void k_head(const float* __restrict__ pooled, const int* __restrict__ gstart,
            const float* __restrict__ lw, const float* __restrict__ lb,
            float* __restrict__ out)
{
  int g = blockIdx.x, t = threadIdx.x;
  __shared__ float lg[NC];
  __shared__ float lse_s;
  int len = gstart[g+1] - gstart[g];
  float inv = 1.f/(float)(len > 0 ? len : 1);
  if(t < NC){
    float acc = lb[t];
    for(int f=0; f<128; f++) acc += pooled[g*128+f]*inv*lw[f*NC + t];
    lg[t] = acc;
  }
  __syncthreads();
  if(t == 0){
    float mx = -1e30f;
    for(int c=0;c<NC;c++) mx = fmaxf(mx, lg[c]);
    float sm = 0.f;
    for(int c=0;c<NC;c++) sm += expf(lg[c]-mx);
    lse_s = mx + logf(sm);
  }
  __syncthreads();
  if(t < NC) out[g*NC + t] = lg[t] - lse_s;
}

// ---------------- launch (14 dispatches) ----------------
extern "C" void kernel_launch(void* const* d_in, const int* in_sizes, int n_in,
                              void* d_out, int out_size, void* d_ws, size_t ws_size,
                              hipStream_t stream)
{
  const float* x    = (const float*)d_in[0];
  const int*   ei   = (const int*)d_in[1];
  const int*   batch= (const int*)d_in[2];
  const float* w1   = (const float*)d_in[3];
  const float* b1   = (const float*)d_in[4];
  const float* w2   = (const float*)d_in[5];
  const float* b2   = (const float*)d_in[6];
  const float* w3   = (const float*)d_in[7];
  const float* b3   = (const float*)d_in[8];
  const float* g1w  = (const float*)d_in[9];
  const float* g1b  = (const float*)d_in[10];
  const float* g1a  = (const float*)d_in[11];
  const float* g2w  = (const float*)d_in[12];
  const float* g2b  = (const float*)d_in[13];
  const float* g2a  = (const float*)d_in[14];
  const float* g3w  = (const float*)d_in[15];
  const float* g3b  = (const float*)d_in[16];
  const float* g3a  = (const float*)d_in[17];
  const float* lw   = (const float*)d_in[18];
  const float* lb   = (const float*)d_in[19];
  float* out = (float*)d_out;

  char* p = (char*)d_ws;
  auto take = [&](size_t nbytes){ char* q = p; p += (nbytes + 255) & ~(size_t)255; return q; };
  ushort* gbuf    = (ushort*)take((size_t)NN*HD*2);
  ushort* bufB    = (ushort*)take((size_t)NN*HD*2);
  ushort* wT      = (ushort*)take((size_t)3*HD*HD*2);
  unsigned* ebuf  = (unsigned*)take((size_t)NBKT*BCAP*4);
  int*   srcs     = (int*)  take((size_t)NE*4);
  int*   rowstart = (int*)  take((size_t)(NN+1)*4);
  float* dinv     = (float*)take((size_t)NN*4);
  int*   cursor0  = (int*)  take((size_t)NBKT*4);
  int*   gstart   = (int*)  take((size_t)(NG+1)*4);
  float* Sbase    = (float*)take((size_t)(3*2*NG*HD + NG*HD)*4);  // 3x(S1,S2) + pooled
  if((size_t)(p - (char*)d_ws) > ws_size) return;  // workspace too small: fail visibly

  float* SL1  = Sbase;
  float* SL1b = Sbase + 1*NG*HD;
  float* SL2  = Sbase + 2*NG*HD;
  float* SL2b = Sbase + 3*NG*HD;
  float* SL3  = Sbase + 4*NG*HD;
  float* SL3b = Sbase + 5*NG*HD;
  float* pooled = Sbase + 6*NG*HD;

  k_init <<<409, 256, 0, stream>>>(batch, gstart, w1, w2, w3, wT, cursor0, rowstart, Sbase);
  k_bin  <<<BIN_BLOCKS, 256, 0, stream>>>(ei, cursor0, ebuf);
  k_sort <<<NBKT, 256, 0, stream>>>(ebuf, cursor0, srcs, rowstart, dinv);

  const int GB = (NN + 127)/128;     // 782
  const int AB = NN/8;               // 12500

  // ---- layer 1 ----
  k_gemm<0><<<GB, 256, 0, stream>>>(x, wT, gbuf, dinv, batch,
                                    nullptr, nullptr, nullptr, nullptr, nullptr, gstart);
  k_agg<<<AB, 256, 0, stream>>>(gbuf, rowstart, srcs, dinv, b1, bufB);
  k_stats<<<dim3(NG, STAT_CH), 128, 0, stream>>>(bufB, gstart, SL1, SL1b);

  // ---- layer 2 ----
  k_gemm<1><<<GB, 256, 0, stream>>>(bufB, wT + 16384, gbuf, dinv, batch,
                                    g1w, g1b, g1a, SL1, SL1b, gstart);
  k_agg<<<AB, 256, 0, stream>>>(gbuf, rowstart, srcs, dinv, b2, bufB);
  k_stats<<<dim3(NG, STAT_CH), 128, 0, stream>>>(bufB, gstart, SL2, SL2b);

  // ---- layer 3 ----
  k_gemm<1><<<GB, 256, 0, stream>>>(bufB, wT + 32768, gbuf, dinv, batch,
                                    g2w, g2b, g2a, SL2, SL2b, gstart);
  k_agg<<<AB, 256, 0, stream>>>(gbuf, rowstart, srcs, dinv, b3, bufB);
  k_stats<<<dim3(NG, STAT_CH), 128, 0, stream>>>(bufB, gstart, SL3, SL3b);

  // ---- pool + head ----
  k_pool<<<dim3(NG, POOL_CH), 128, 0, stream>>>(bufB, gstart, g3w, g3b, g3a, SL3, SL3b, pooled);
  k_head<<<NG, 64, 0, stream>>>(pooled, gstart, lw, lb, out);
}

// Round 13
// 358.924 us; speedup vs baseline: 3.5767x; 1.1652x over previous
//
#include <hip/hip_runtime.h>

#define NN 100000
#define NE 1600000
#define HD 128
#define NG 128
#define NC 10
#define EPSV 1e-5f

#define BSH 9                      // 512 dst nodes per bucket
#define NBKT ((NN + 511) >> 9)     // 196
#define BCAP 9216                  // slots per bucket region (mean 8192, sigma~90 -> +11 sigma)
#define BIN_BLOCKS ((NE + 4095) / 4096)  // 391
#define STAT_CH 8
#define POOL_CH 16

typedef __attribute__((ext_vector_type(8))) short short8;
typedef __attribute__((ext_vector_type(4))) float f32x4;

__device__ __forceinline__ float b2f(ushort u){ return __uint_as_float(((unsigned)u)<<16); }
__device__ __forceinline__ ushort f2b(float f){
  unsigned u = __float_as_uint(f);
  unsigned r = (u + 0x7FFFu + ((u>>16)&1u)) >> 16;   // RNE
  return (ushort)r;
}

// ---------------- init: granges + weight-prep + zeroing (S, cursor0) ----------------
__global__ __launch_bounds__(256)
void k_init(const int* __restrict__ batch, int* __restrict__ gstart,
            const float* __restrict__ w1, const float* __restrict__ w2,
            const float* __restrict__ w3, ushort* __restrict__ wT,
            int* __restrict__ cursor0, int* __restrict__ rowstart,
            float* __restrict__ zero_base)
{
  int b = blockIdx.x, t = threadIdx.x;
  if(b < 391){                       // granges: batch sorted -> contiguous segments
    int n = b*256 + t;
    if(n >= NN) return;
    int bb = batch[n];
    if(n == 0){
      for(int g=0; g<=bb; g++) gstart[g] = 0;
      int last = batch[NN-1];
      for(int g=last+1; g<=NG; g++) gstart[g] = NN;
    } else {
      int bp = batch[n-1];
      for(int g=bp+1; g<=bb; g++) gstart[g] = n;
    }
  } else if(b < 394){                // wT[layer][h][k] = bf16(w[k][h])
    const float* w = (b == 391) ? w1 : (b == 392) ? w2 : w3;
    ushort* o = wT + (b-391)*16384;
    #pragma unroll 4
    for(int i=0;i<64;i++){
      int e = i*256 + t;
      o[(e & 127)*128 + (e >> 7)] = f2b(w[e]);
    }
  } else if(b < 408){                // zero 3x(S1,S2)+pooled = 114688 floats
    #pragma unroll 8
    for(int i=0;i<32;i++) zero_base[(size_t)(b-394)*8192 + i*256 + t] = 0.f;
  } else {
    if(t < NBKT) cursor0[t] = 0;
    if(t == 0)   rowstart[NN] = NE;
  }
}

// ---------------- bin: edges -> per-bucket regions (LDS-staged, contiguous writes) ----------
__global__ __launch_bounds__(256) void k_bin(const int* __restrict__ ei, int* __restrict__ cursor0,
                                             unsigned* __restrict__ ebuf){
  __shared__ unsigned eb[4096];
  __shared__ unsigned char bb4[4096];
  __shared__ int hist[NBKT], lstart[NBKT], lcur[NBKT], rbase[NBKT];
  __shared__ int scanbuf[256];
  int t = threadIdx.x;
  if(t < NBKT) hist[t] = 0;
  __syncthreads();
  int base = blockIdx.x*4096;
  int nv = NE - base; if(nv > 4096) nv = 4096;
  int se[16], de[16];
  #pragma unroll
  for(int i=0;i<16;i++){
    int e = base + i*256 + t;
    if(e < NE){ se[i] = ei[e]; de[i] = ei[NE + e]; atomicAdd(&hist[de[i] >> BSH], 1); }
  }
  __syncthreads();
  int v = (t < NBKT) ? hist[t] : 0;
  scanbuf[t] = v; __syncthreads();
  for(int off=1; off<256; off<<=1){
    int y = scanbuf[t]; int z = (t>=off)?scanbuf[t-off]:0;
    __syncthreads(); scanbuf[t] = y+z; __syncthreads();
  }
  if(t < NBKT){
    int excl = (t>0)?scanbuf[t-1]:0;
    lstart[t] = excl; lcur[t] = excl;
    if(hist[t]) rbase[t] = t*BCAP + atomicAdd(&cursor0[t], hist[t]);
  }
  __syncthreads();
  #pragma unroll
  for(int i=0;i<16;i++){
    int e = base + i*256 + t;
    if(e < NE){
      int b = de[i] >> BSH;
      int idx = atomicAdd(&lcur[b], 1);
      eb[idx] = ((unsigned)(de[i] & 511) << 17) | (unsigned)se[i];
      bb4[idx] = (unsigned char)b;
    }
  }
  __syncthreads();
  #pragma unroll
  for(int i=0;i<16;i++){
    int slot = i*256 + t;
    if(slot < nv){
      int b = bb4[slot];
      ebuf[rbase[b] + (slot - lstart[b])] = eb[slot];
    }
  }
}

// ---------------- sort: per-bucket counting sort -> contiguous CSR (rowstart, srcs, dinv) ----
__global__ __launch_bounds__(256) void k_sort(const unsigned* __restrict__ ebuf,
                                              const int* __restrict__ cursor0,
                                              int* __restrict__ srcs, int* __restrict__ rowstart,
                                              float* __restrict__ dinv){
  __shared__ int hist[512], cur[512];
  __shared__ int scanbuf[256];
  int b = blockIdx.x, t = threadIdx.x;
  int v = (t < NBKT) ? cursor0[t] : 0;
  scanbuf[t] = v; __syncthreads();
  for(int off=1; off<256; off<<=1){
    int y = scanbuf[t]; int z = (t>=off)?scanbuf[t-off]:0;
    __syncthreads(); scanbuf[t] = y+z; __syncthreads();
  }
  const int e0 = (b>0) ? scanbuf[b-1] : 0;
  const int cnt = cursor0[b];
  const unsigned* reg = ebuf + (size_t)b*BCAP;
  hist[t] = 0; hist[t+256] = 0;
  __syncthreads();
  for(int i = t; i < cnt; i += 256)
    atomicAdd(&hist[reg[i] >> 17], 1);
  __syncthreads();
  int s0 = hist[2*t], s1 = hist[2*t+1];
  scanbuf[t] = s0 + s1; __syncthreads();
  for(int off=1; off<256; off<<=1){
    int y = scanbuf[t]; int z = (t>=off)?scanbuf[t-off]:0;
    __syncthreads(); scanbuf[t] = y+z; __syncthreads();
  }
  int excl = (t>0)?scanbuf[t-1]:0;
  cur[2*t] = excl; cur[2*t+1] = excl + s0;
  int d0 = (b << BSH) + 2*t, d1 = d0 + 1;
  if(d0 < NN){ rowstart[d0] = e0 + excl;      dinv[d0] = rsqrtf((float)(s0 + 1)); }
  if(d1 < NN){ rowstart[d1] = e0 + excl + s0; dinv[d1] = rsqrtf((float)(s1 + 1)); }
  __syncthreads();
  for(int i = t; i < cnt; i += 256){
    unsigned pk = reg[i];
    int dl = pk >> 17;
    int pos = e0 + atomicAdd(&cur[dl], 1);
    srcs[pos] = (int)(pk & 0x1FFFFu);
  }
}

// ---------------- MFMA GEMM: g[node][h] = bf16( dinv[node] * (norm_relu(in[node]) @ w)[h] ) ----
// NORM=0: raw fp32 input (layer 1). NORM=1: bf16 input + GraphNorm (inline from S1/S2) + ReLU.
// Epilogue: acc -> LDS (bf16) -> coalesced ushort8 stores (16B/lane).
template<int NORM>
__global__ __launch_bounds__(256)
void k_gemm(const void* __restrict__ in_, const ushort* __restrict__ wT,
            ushort* __restrict__ g, const float* __restrict__ dinv,
            const int* __restrict__ batch,
            const float* __restrict__ gw, const float* __restrict__ gb,
            const float* __restrict__ ga, const float* __restrict__ S1,
            const float* __restrict__ S2, const int* __restrict__ gstart)
{
  __shared__ ushort lds_a[128*136];
  __shared__ float sdinv[128];
  const int t = threadIdx.x;
  const int row0 = blockIdx.x * 128;
  {
    const int l = t & 31;
    const int rr = t >> 5;
    if(t < 128){
      int node = row0 + t;
      sdinv[t] = (node < NN) ? dinv[node] : 0.f;
    }
    float4 gwv, gbv, gav;
    float4 amv = make_float4(0.f,0.f,0.f,0.f), rsv = make_float4(0.f,0.f,0.f,0.f);
    int gprev = -1;
    if(NORM){
      gwv = ((const float4*)gw)[l]; gbv = ((const float4*)gb)[l];
      gav = ((const float4*)ga)[l];
    }
    #pragma unroll 4
    for(int rb = 0; rb < 16; rb++){
      int r = rb*8 + rr;
      int node = row0 + r;
      float4 v = make_float4(0.f,0.f,0.f,0.f);
      if(node < NN){
        if(NORM){
          ushort4 raw = ((const ushort4*)in_)[(size_t)node*32 + l];
          v = make_float4(b2f(raw.x), b2f(raw.y), b2f(raw.z), b2f(raw.w));
          int gg = batch[node];
          if(gg != gprev){
            gprev = gg;
            int c0 = gstart[gg], c1 = gstart[gg+1];
            float inv = 1.f/(float)((c1-c0) > 0 ? (c1-c0) : 1);
            float4 s1v = ((const float4*)S1)[gg*32 + l];
            float4 s2v = ((const float4*)S2)[gg*32 + l];
            float m, ex2, a;
            m = s1v.x*inv; ex2 = s2v.x*inv; a = gav.x;
            amv.x = a*m; rsv.x = rsqrtf(ex2 - (2.f*a - a*a)*m*m + EPSV);
            m = s1v.y*inv; ex2 = s2v.y*inv; a = gav.y;
            amv.y = a*m; rsv.y = rsqrtf(ex2 - (2.f*a - a*a)*m*m + EPSV);
            m = s1v.z*inv; ex2 = s2v.z*inv; a = gav.z;
            amv.z = a*m; rsv.z = rsqrtf(ex2 - (2.f*a - a*a)*m*m + EPSV);
            m = s1v.w*inv; ex2 = s2v.w*inv; a = gav.w;
            amv.w = a*m; rsv.w = rsqrtf(ex2 - (2.f*a - a*a)*m*m + EPSV);
          }
          v.x = fmaxf(gwv.x*(v.x-amv.x)*rsv.x + gbv.x, 0.f);
          v.y = fmaxf(gwv.y*(v.y-amv.y)*rsv.y + gbv.y, 0.f);
          v.z = fmaxf(gwv.z*(v.z-amv.z)*rsv.z + gbv.z, 0.f);
          v.w = fmaxf(gwv.w*(v.w-amv.w)*rsv.w + gbv.w, 0.f);
        } else {
          v = ((const float4*)in_)[(size_t)node*32 + l];
        }
      }
      ushort4 b4;
      b4.x = f2b(v.x); b4.y = f2b(v.y); b4.z = f2b(v.z); b4.w = f2b(v.w);
      *(ushort4*)(lds_a + r*136 + l*4) = b4;
    }
  }
  __syncthreads();

  const int wv = t >> 6, l = t & 63, lc = l & 15, lk = l >> 4;
  short8 bfrag[2][4];
  #pragma unroll
  for(int tt=0; tt<2; tt++){
    int col = wv*32 + tt*16 + lc;
    #pragma unroll
    for(int s=0; s<4; s++)
      bfrag[tt][s] = *(const short8*)(wT + col*128 + s*32 + lk*8);
  }
  f32x4 acc[8][2];
  #pragma unroll
  for(int m=0;m<8;m++){ acc[m][0] = (f32x4)0.f; acc[m][1] = (f32x4)0.f; }
  #pragma unroll
  for(int m=0; m<8; m++){
    const ushort* ap = lds_a + (m*16 + lc)*136 + lk*8;
    #pragma unroll
    for(int s=0; s<4; s++){
      short8 a = *(const short8*)(ap + s*32);
      acc[m][0] = __builtin_amdgcn_mfma_f32_16x16x32_bf16(a, bfrag[0][s], acc[m][0], 0, 0, 0);
      acc[m][1] = __builtin_amdgcn_mfma_f32_16x16x32_bf16(a, bfrag[1][s], acc[m][1], 0, 0, 0);
    }
  }
  __syncthreads();     // MFMA reads of lds_a done; reuse as C staging tile

  #pragma unroll
  for(int m=0; m<8; m++){
    #pragma unroll
    for(int tt=0; tt<2; tt++){
      int colg = wv*32 + tt*16 + lc;
      #pragma unroll
      for(int r=0; r<4; r++){
        int row = m*16 + lk*4 + r;
        lds_a[row*136 + colg] = f2b(acc[m][tt][r] * sdinv[row]);
      }
    }
  }
  __syncthreads();
  {
    ushort* gout = g + (size_t)row0*128;
    int maxrow = NN - row0; if(maxrow > 128) maxrow = 128;
    #pragma unroll
    for(int i=0; i<8; i++){
      int idx = i*256 + t;
      int row = idx >> 4, grp = idx & 15;
      if(row < maxrow){
        short8 c8 = *(const short8*)(lds_a + row*136 + grp*8);
        *(short8*)(gout + row*128 + grp*8) = c8;
      }
    }
  }
}

// ---------------- lean aggregation over dst-sorted edges (bf16 gather + bf16 out) ----------
__global__ __launch_bounds__(256)
void k_agg(const ushort* __restrict__ g, const int* __restrict__ rowstart,
           const int* __restrict__ srcs, const float* __restrict__ dinv,
           const float* __restrict__ bias, ushort* __restrict__ outp)
{
  const int lane = threadIdx.x & 31;
  const int node = blockIdx.x*8 + (threadIdx.x >> 5);
  const int e0 = rowstart[node], e1 = rowstart[node+1];
  float ax=0.f, ay=0.f, az=0.f, aw=0.f;
  float bx=0.f, by=0.f, bz=0.f, bw=0.f;
  const ushort4* gp = (const ushort4*)g;
  int e = e0;
  for(; e+7 < e1; e += 8){
    int si[8];
    #pragma unroll
    for(int i=0;i<8;i++) si[i] = srcs[e+i];
    ushort4 v[8];
    #pragma unroll
    for(int i=0;i<8;i++) v[i] = gp[(size_t)si[i]*32 + lane];
    #pragma unroll
    for(int i=0;i<8;i++){
      if(i&1){ bx += b2f(v[i].x); by += b2f(v[i].y); bz += b2f(v[i].z); bw += b2f(v[i].w); }
      else   { ax += b2f(v[i].x); ay += b2f(v[i].y); az += b2f(v[i].z); aw += b2f(v[i].w); }
    }
  }
  for(; e+3 < e1; e += 4){
    int si[4];
    #pragma unroll
    for(int i=0;i<4;i++) si[i] = srcs[e+i];
    ushort4 v[4];
    #pragma unroll
    for(int i=0;i<4;i++) v[i] = gp[(size_t)si[i]*32 + lane];
    #pragma unroll
    for(int i=0;i<4;i++){
      if(i&1){ bx += b2f(v[i].x); by += b2f(v[i].y); bz += b2f(v[i].z); bw += b2f(v[i].w); }
      else   { ax += b2f(v[i].x); ay += b2f(v[i].y); az += b2f(v[i].z); aw += b2f(v[i].w); }
    }
  }
  for(; e < e1; e++){
    ushort4 v = gp[(size_t)srcs[e]*32 + lane];
    ax += b2f(v.x); ay += b2f(v.y); az += b2f(v.z); aw += b2f(v.w);
  }
  ushort4 vs = gp[(size_t)node*32 + lane];
  float dv = dinv[node];
  float4 bv = ((const float4*)bias)[lane];
  ushort4 o4;
  o4.x = f2b(dv*(ax+bx+b2f(vs.x))+bv.x);
  o4.y = f2b(dv*(ay+by+b2f(vs.y))+bv.y);
  o4.z = f2b(dv*(az+bz+b2f(vs.z))+bv.z);
  o4.w = f2b(dv*(aw+bw+b2f(vs.w))+bv.w);
  ((ushort4*)outp)[(size_t)node*32 + lane] = o4;
}

// ---------------- per-graph moments, vectorized: ushort8 loads, 8 rows/iter ----------------
// thread t: feature-octet grp=t&15, row-offset ro=t>>4
__global__ __launch_bounds__(128)
void k_stats(const ushort* __restrict__ x, const int* __restrict__ gstart,
             float* __restrict__ S1, float* __restrict__ S2)
{
  __shared__ float sb1[128][9], sb2[128][9];   // +1 pad: conflict-free
  int g = blockIdx.x, ch = blockIdx.y, t = threadIdx.x;
  int grp = t & 15, ro = t >> 4;
  int s = gstart[g], e = gstart[g+1];
  int len = e - s;
  int i0 = s + (int)((long long)len * ch / STAT_CH);
  int i1 = s + (int)((long long)len * (ch+1) / STAT_CH);
  float a1[8], a2[8];
  #pragma unroll
  for(int k=0;k<8;k++){ a1[k]=0.f; a2[k]=0.f; }
  for(int n = i0 + ro; n < i1; n += 8){
    short8 v8 = *(const short8*)(x + (size_t)n*128 + grp*8);
    #pragma unroll
    for(int k=0;k<8;k++){
      float v = b2f((ushort)v8[k]);
      a1[k] += v; a2[k] += v*v;
    }
  }
  #pragma unroll
  for(int k=0;k<8;k++){ sb1[t][k]=a1[k]; sb2[t][k]=a2[k]; }
  __syncthreads();
  if(ro < 4){
    #pragma unroll
    for(int k=0;k<8;k++){ sb1[t][k]+=sb1[t+64][k]; sb2[t][k]+=sb2[t+64][k]; }
  }
  __syncthreads();
  if(ro < 2){
    #pragma unroll
    for(int k=0;k<8;k++){ sb1[t][k]+=sb1[t+32][k]; sb2[t][k]+=sb2[t+32][k]; }
  }
  __syncthreads();
  if(ro < 1){
    #pragma unroll
    for(int k=0;k<8;k++){ sb1[t][k]+=sb1[t+16][k]; sb2[t][k]+=sb2[t+16][k]; }
  }
  __syncthreads();
  if(t < 16 && i1 > i0){
    #pragma unroll
    for(int k=0;k<8;k++){
      atomicAdd(&S1[g*128 + t*8 + k], sb1[t][k]);
      atomicAdd(&S2[g*128 + t*8 + k], sb2[t][k]);
    }
  }
}

// ---------------- pool, vectorized: relu(norm(x)) summed; norm inline from S1/S2 -----------
__global__ __launch_bounds__(128)
void k_pool(const ushort* __restrict__ x, const int* __restrict__ gstart,
            const float* __restrict__ gw, const float* __restrict__ gb,
            const float* __restrict__ ga, const float* __restrict__ S1,
            const float* __restrict__ S2, float* __restrict__ pooled)
{
  __shared__ float sb[128][9];
  int g = blockIdx.x, ch = blockIdx.y, t = threadIdx.x;
  int grp = t & 15, ro = t >> 4;
  int s = gstart[g], e = gstart[g+1];
  int len = e - s;
  int i0 = s + (int)((long long)len * ch / POOL_CH);
  int i1 = s + (int)((long long)len * (ch+1) / POOL_CH);
  float inv = 1.f/(float)(len > 0 ? len : 1);
  float am[8], rs[8], wv[8], bv[8];
  #pragma unroll
  for(int k=0;k<8;k++){
    int f = grp*8 + k;
    float a = ga[f];
    float m = S1[g*128+f]*inv, ex2 = S2[g*128+f]*inv;
    am[k] = a*m;
    rs[k] = rsqrtf(ex2 - (2.f*a - a*a)*m*m + EPSV);
    wv[k] = gw[f]; bv[k] = gb[f];
  }
  float acc[8];
  #pragma unroll
  for(int k=0;k<8;k++) acc[k] = 0.f;
  for(int n = i0 + ro; n < i1; n += 8){
    short8 v8 = *(const short8*)(x + (size_t)n*128 + grp*8);
    #pragma unroll
    for(int k=0;k<8;k++){
      float v = wv[k]*(b2f((ushort)v8[k]) - am[k])*rs[k] + bv[k];
      acc[k] += fmaxf(v, 0.f);
    }
  }
  #pragma unroll
  for(int k=0;k<8;k++) sb[t][k] = acc[k];
  __syncthreads();
  if(ro < 4){
    #pragma unroll
    for(int k=0;k<8;k++) sb[t][k] += sb[t+64][k];
  }
  __syncthreads();
  if(ro < 2){
    #pragma unroll
    for(int k=0;k<8;k++) sb[t][k] += sb[t+32][k];
  }
  __syncthreads();
  if(ro < 1){
    #pragma unroll
    for(int k=0;k<8;k++) sb[t][k] += sb[t+16][k];
  }
  __syncthreads();
  if(t < 16 && i1 > i0){
    #pragma unroll
    for(int k=0;k<8;k++)
      atomicAdd(&pooled[g*128 + t*8 + k], sb[t][k]);
  }
}

// ---------------- head: logits = pooled/cnt @ lw + lb, log_softmax ----------------
__global__ __launch_bounds__(64)
void k_head(const float* __restrict__ pooled, const int* __restrict__ gstart,
            const float* __restrict__ lw, const float* __restrict__ lb,
            float* __restrict__ out)
{
  int g = blockIdx.x, t = threadIdx.x;
  __shared__ float lg[NC];
  __shared__ float lse_s;
  int len = gstart[g+1] - gstart[g];
  float inv = 1.f/(float)(len > 0 ? len : 1);
  if(t < NC){
    float acc = lb[t];
    for(int f=0; f<128; f++) acc += pooled[g*128+f]*inv*lw[f*NC + t];
    lg[t] = acc;
  }
  __syncthreads();
  if(t == 0){
    float mx = -1e30f;
    for(int c=0;c<NC;c++) mx = fmaxf(mx, lg[c]);
    float sm = 0.f;
    for(int c=0;c<NC;c++) sm += expf(lg[c]-mx);
    lse_s = mx + logf(sm);
  }
  __syncthreads();
  if(t < NC) out[g*NC + t] = lg[t] - lse_s;
}

// ---------------- launch (14 dispatches) ----------------
extern "C" void kernel_launch(void* const* d_in, const int* in_sizes, int n_in,
                              void* d_out, int out_size, void* d_ws, size_t ws_size,
                              hipStream_t stream)
{
  const float* x    = (const float*)d_in[0];
  const int*   ei   = (const int*)d_in[1];
  const int*   batch= (const int*)d_in[2];
  const float* w1   = (const float*)d_in[3];
  const float* b1   = (const float*)d_in[4];
  const float* w2   = (const float*)d_in[5];
  const float* b2   = (const float*)d_in[6];
  const float* w3   = (const float*)d_in[7];
  const float* b3   = (const float*)d_in[8];
  const float* g1w  = (const float*)d_in[9];
  const float* g1b  = (const float*)d_in[10];
  const float* g1a  = (const float*)d_in[11];
  const float* g2w  = (const float*)d_in[12];
  const float* g2b  = (const float*)d_in[13];
  const float* g2a  = (const float*)d_in[14];
  const float* g3w  = (const float*)d_in[15];
  const float* g3b  = (const float*)d_in[16];
  const float* g3a  = (const float*)d_in[17];
  const float* lw   = (const float*)d_in[18];
  const float* lb   = (const float*)d_in[19];
  float* out = (float*)d_out;

  char* p = (char*)d_ws;
  auto take = [&](size_t nbytes){ char* q = p; p += (nbytes + 255) & ~(size_t)255; return q; };
  ushort* gbuf    = (ushort*)take((size_t)NN*HD*2);
  ushort* bufB    = (ushort*)take((size_t)NN*HD*2);
  ushort* wT      = (ushort*)take((size_t)3*HD*HD*2);
  unsigned* ebuf  = (unsigned*)take((size_t)NBKT*BCAP*4);
  int*   srcs     = (int*)  take((size_t)NE*4);
  int*   rowstart = (int*)  take((size_t)(NN+1)*4);
  float* dinv     = (float*)take((size_t)NN*4);
  int*   cursor0  = (int*)  take((size_t)NBKT*4);
  int*   gstart   = (int*)  take((size_t)(NG+1)*4);
  float* Sbase    = (float*)take((size_t)(3*2*NG*HD + NG*HD)*4);  // 3x(S1,S2) + pooled
  if((size_t)(p - (char*)d_ws) > ws_size) return;  // workspace too small: fail visibly

  float* SL1  = Sbase;
  float* SL1b = Sbase + 1*NG*HD;
  float* SL2  = Sbase + 2*NG*HD;
  float* SL2b = Sbase + 3*NG*HD;
  float* SL3  = Sbase + 4*NG*HD;
  float* SL3b = Sbase + 5*NG*HD;
  float* pooled = Sbase + 6*NG*HD;

  k_init <<<409, 256, 0, stream>>>(batch, gstart, w1, w2, w3, wT, cursor0, rowstart, Sbase);
  k_bin  <<<BIN_BLOCKS, 256, 0, stream>>>(ei, cursor0, ebuf);
  k_sort <<<NBKT, 256, 0, stream>>>(ebuf, cursor0, srcs, rowstart, dinv);

  const int GB = (NN + 127)/128;     // 782
  const int AB = NN/8;               // 12500

  // ---- layer 1 ----
  k_gemm<0><<<GB, 256, 0, stream>>>(x, wT, gbuf, dinv, batch,
                                    nullptr, nullptr, nullptr, nullptr, nullptr, gstart);
  k_agg<<<AB, 256, 0, stream>>>(gbuf, rowstart, srcs, dinv, b1, bufB);
  k_stats<<<dim3(NG, STAT_CH), 128, 0, stream>>>(bufB, gstart, SL1, SL1b);

  // ---- layer 2 ----
  k_gemm<1><<<GB, 256, 0, stream>>>(bufB, wT + 16384, gbuf, dinv, batch,
                                    g1w, g1b, g1a, SL1, SL1b, gstart);
  k_agg<<<AB, 256, 0, stream>>>(gbuf, rowstart, srcs, dinv, b2, bufB);
  k_stats<<<dim3(NG, STAT_CH), 128, 0, stream>>>(bufB, gstart, SL2, SL2b);

  // ---- layer 3 ----
  k_gemm<1><<<GB, 256, 0, stream>>>(bufB, wT + 32768, gbuf, dinv, batch,
                                    g2w, g2b, g2a, SL2, SL2b, gstart);
  k_agg<<<AB, 256, 0, stream>>>(gbuf, rowstart, srcs, dinv, b3, bufB);
  k_stats<<<dim3(NG, STAT_CH), 128, 0, stream>>>(bufB, gstart, SL3, SL3b);

  // ---- pool + head ----
  k_pool<<<dim3(NG, POOL_CH), 128, 0, stream>>>(bufB, gstart, g3w, g3b, g3a, SL3, SL3b, pooled);
  k_head<<<NG, 64, 0, stream>>>(pooled, gstart, lw, lb, out);
}

// Round 14
// 355.234 us; speedup vs baseline: 3.6139x; 1.0104x over previous
//
#include <hip/hip_runtime.h>

#define NN 100000
#define NE 1600000
#define HD 128
#define NG 128
#define NC 10
#define EPSV 1e-5f

#define BSH 9                      // 512 dst nodes per bucket
#define NBKT ((NN + 511) >> 9)     // 196
#define BCAP 9216                  // slots per bucket region (mean 8192, sigma~90 -> +11 sigma)
#define BIN_BLOCKS ((NE + 4095) / 4096)  // 391
#define STAT_CH 8
#define POOL_CH 16

typedef __attribute__((ext_vector_type(8))) short short8;
typedef __attribute__((ext_vector_type(4))) float f32x4;

__device__ __forceinline__ float b2f(ushort u){ return __uint_as_float(((unsigned)u)<<16); }
__device__ __forceinline__ ushort f2b(float f){
  unsigned u = __float_as_uint(f);
  unsigned r = (u + 0x7FFFu + ((u>>16)&1u)) >> 16;   // RNE
  return (ushort)r;
}

// ---------------- init: granges + weight-prep + zeroing (S, cursor0) ----------------
__global__ __launch_bounds__(256)
void k_init(const int* __restrict__ batch, int* __restrict__ gstart,
            const float* __restrict__ w1, const float* __restrict__ w2,
            const float* __restrict__ w3, ushort* __restrict__ wT,
            int* __restrict__ cursor0, int* __restrict__ rowstart,
            float* __restrict__ zero_base)
{
  int b = blockIdx.x, t = threadIdx.x;
  if(b < 391){                       // granges: batch sorted -> contiguous segments
    int n = b*256 + t;
    if(n >= NN) return;
    int bb = batch[n];
    if(n == 0){
      for(int g=0; g<=bb; g++) gstart[g] = 0;
      int last = batch[NN-1];
      for(int g=last+1; g<=NG; g++) gstart[g] = NN;
    } else {
      int bp = batch[n-1];
      for(int g=bp+1; g<=bb; g++) gstart[g] = n;
    }
  } else if(b < 394){                // wT[layer][h][k] = bf16(w[k][h])
    const float* w = (b == 391) ? w1 : (b == 392) ? w2 : w3;
    ushort* o = wT + (b-391)*16384;
    #pragma unroll 4
    for(int i=0;i<64;i++){
      int e = i*256 + t;
      o[(e & 127)*128 + (e >> 7)] = f2b(w[e]);
    }
  } else if(b < 408){                // zero 3x(S1,S2)+pooled = 114688 floats
    #pragma unroll 8
    for(int i=0;i<32;i++) zero_base[(size_t)(b-394)*8192 + i*256 + t] = 0.f;
  } else {
    if(t < NBKT) cursor0[t] = 0;
    if(t == 0)   rowstart[NN] = NE;
  }
}

// ---------------- bin: edges -> per-bucket regions (LDS-staged, contiguous writes) ----------
__global__ __launch_bounds__(256) void k_bin(const int* __restrict__ ei, int* __restrict__ cursor0,
                                             unsigned* __restrict__ ebuf){
  __shared__ unsigned eb[4096];
  __shared__ unsigned char bb4[4096];
  __shared__ int hist[NBKT], lstart[NBKT], lcur[NBKT], rbase[NBKT];
  __shared__ int scanbuf[256];
  int t = threadIdx.x;
  if(t < NBKT) hist[t] = 0;
  __syncthreads();
  int base = blockIdx.x*4096;
  int nv = NE - base; if(nv > 4096) nv = 4096;
  int se[16], de[16];
  #pragma unroll
  for(int i=0;i<16;i++){
    int e = base + i*256 + t;
    if(e < NE){ se[i] = ei[e]; de[i] = ei[NE + e]; atomicAdd(&hist[de[i] >> BSH], 1); }
  }
  __syncthreads();
  int v = (t < NBKT) ? hist[t] : 0;
  scanbuf[t] = v; __syncthreads();
  for(int off=1; off<256; off<<=1){
    int y = scanbuf[t]; int z = (t>=off)?scanbuf[t-off]:0;
    __syncthreads(); scanbuf[t] = y+z; __syncthreads();
  }
  if(t < NBKT){
    int excl = (t>0)?scanbuf[t-1]:0;
    lstart[t] = excl; lcur[t] = excl;
    if(hist[t]) rbase[t] = t*BCAP + atomicAdd(&cursor0[t], hist[t]);
  }
  __syncthreads();
  #pragma unroll
  for(int i=0;i<16;i++){
    int e = base + i*256 + t;
    if(e < NE){
      int b = de[i] >> BSH;
      int idx = atomicAdd(&lcur[b], 1);
      eb[idx] = ((unsigned)(de[i] & 511) << 17) | (unsigned)se[i];
      bb4[idx] = (unsigned char)b;
    }
  }
  __syncthreads();
  #pragma unroll
  for(int i=0;i<16;i++){
    int slot = i*256 + t;
    if(slot < nv){
      int b = bb4[slot];
      ebuf[rbase[b] + (slot - lstart[b])] = eb[slot];
    }
  }
}

// ---------------- sort: per-bucket counting sort -> contiguous CSR (rowstart, srcs, dinv) ----
__global__ __launch_bounds__(256) void k_sort(const unsigned* __restrict__ ebuf,
                                              const int* __restrict__ cursor0,
                                              int* __restrict__ srcs, int* __restrict__ rowstart,
                                              float* __restrict__ dinv){
  __shared__ int hist[512], cur[512];
  __shared__ int scanbuf[256];
  int b = blockIdx.x, t = threadIdx.x;
  int v = (t < NBKT) ? cursor0[t] : 0;
  scanbuf[t] = v; __syncthreads();
  for(int off=1; off<256; off<<=1){
    int y = scanbuf[t]; int z = (t>=off)?scanbuf[t-off]:0;
    __syncthreads(); scanbuf[t] = y+z; __syncthreads();
  }
  const int e0 = (b>0) ? scanbuf[b-1] : 0;
  const int cnt = cursor0[b];
  const unsigned* reg = ebuf + (size_t)b*BCAP;
  hist[t] = 0; hist[t+256] = 0;
  __syncthreads();
  for(int i = t; i < cnt; i += 256)
    atomicAdd(&hist[reg[i] >> 17], 1);
  __syncthreads();
  int s0 = hist[2*t], s1 = hist[2*t+1];
  scanbuf[t] = s0 + s1; __syncthreads();
  for(int off=1; off<256; off<<=1){
    int y = scanbuf[t]; int z = (t>=off)?scanbuf[t-off]:0;
    __syncthreads(); scanbuf[t] = y+z; __syncthreads();
  }
  int excl = (t>0)?scanbuf[t-1]:0;
  cur[2*t] = excl; cur[2*t+1] = excl + s0;
  int d0 = (b << BSH) + 2*t, d1 = d0 + 1;
  if(d0 < NN){ rowstart[d0] = e0 + excl;      dinv[d0] = rsqrtf((float)(s0 + 1)); }
  if(d1 < NN){ rowstart[d1] = e0 + excl + s0; dinv[d1] = rsqrtf((float)(s1 + 1)); }
  __syncthreads();
  for(int i = t; i < cnt; i += 256){
    unsigned pk = reg[i];
    int dl = pk >> 17;
    int pos = e0 + atomicAdd(&cur[dl], 1);
    srcs[pos] = (int)(pk & 0x1FFFFu);
  }
}

// ---------------- MFMA GEMM: g[node][h] = bf16( dinv[node] * (norm_relu(in[node]) @ w)[h] ) ----
template<int NORM>
__global__ __launch_bounds__(256)
void k_gemm(const void* __restrict__ in_, const ushort* __restrict__ wT,
            ushort* __restrict__ g, const float* __restrict__ dinv,
            const int* __restrict__ batch,
            const float* __restrict__ gw, const float* __restrict__ gb,
            const float* __restrict__ ga, const float* __restrict__ S1,
            const float* __restrict__ S2, const int* __restrict__ gstart)
{
  __shared__ ushort lds_a[128*136];
  __shared__ float sdinv[128];
  const int t = threadIdx.x;
  const int row0 = blockIdx.x * 128;
  {
    const int l = t & 31;
    const int rr = t >> 5;
    if(t < 128){
      int node = row0 + t;
      sdinv[t] = (node < NN) ? dinv[node] : 0.f;
    }
    float4 gwv, gbv, gav;
    float4 amv = make_float4(0.f,0.f,0.f,0.f), rsv = make_float4(0.f,0.f,0.f,0.f);
    int gprev = -1;
    if(NORM){
      gwv = ((const float4*)gw)[l]; gbv = ((const float4*)gb)[l];
      gav = ((const float4*)ga)[l];
    }
    #pragma unroll 4
    for(int rb = 0; rb < 16; rb++){
      int r = rb*8 + rr;
      int node = row0 + r;
      float4 v = make_float4(0.f,0.f,0.f,0.f);
      if(node < NN){
        if(NORM){
          ushort4 raw = ((const ushort4*)in_)[(size_t)node*32 + l];
          v = make_float4(b2f(raw.x), b2f(raw.y), b2f(raw.z), b2f(raw.w));
          int gg = batch[node];
          if(gg != gprev){
            gprev = gg;
            int c0 = gstart[gg], c1 = gstart[gg+1];
            float inv = 1.f/(float)((c1-c0) > 0 ? (c1-c0) : 1);
            float4 s1v = ((const float4*)S1)[gg*32 + l];
            float4 s2v = ((const float4*)S2)[gg*32 + l];
            float m, ex2, a;
            m = s1v.x*inv; ex2 = s2v.x*inv; a = gav.x;
            amv.x = a*m; rsv.x = rsqrtf(ex2 - (2.f*a - a*a)*m*m + EPSV);
            m = s1v.y*inv; ex2 = s2v.y*inv; a = gav.y;
            amv.y = a*m; rsv.y = rsqrtf(ex2 - (2.f*a - a*a)*m*m + EPSV);
            m = s1v.z*inv; ex2 = s2v.z*inv; a = gav.z;
            amv.z = a*m; rsv.z = rsqrtf(ex2 - (2.f*a - a*a)*m*m + EPSV);
            m = s1v.w*inv; ex2 = s2v.w*inv; a = gav.w;
            amv.w = a*m; rsv.w = rsqrtf(ex2 - (2.f*a - a*a)*m*m + EPSV);
          }
          v.x = fmaxf(gwv.x*(v.x-amv.x)*rsv.x + gbv.x, 0.f);
          v.y = fmaxf(gwv.y*(v.y-amv.y)*rsv.y + gbv.y, 0.f);
          v.z = fmaxf(gwv.z*(v.z-amv.z)*rsv.z + gbv.z, 0.f);
          v.w = fmaxf(gwv.w*(v.w-amv.w)*rsv.w + gbv.w, 0.f);
        } else {
          v = ((const float4*)in_)[(size_t)node*32 + l];
        }
      }
      ushort4 b4;
      b4.x = f2b(v.x); b4.y = f2b(v.y); b4.z = f2b(v.z); b4.w = f2b(v.w);
      *(ushort4*)(lds_a + r*136 + l*4) = b4;
    }
  }
  __syncthreads();

  const int wv = t >> 6, l = t & 63, lc = l & 15, lk = l >> 4;
  short8 bfrag[2][4];
  #pragma unroll
  for(int tt=0; tt<2; tt++){
    int col = wv*32 + tt*16 + lc;
    #pragma unroll
    for(int s=0; s<4; s++)
      bfrag[tt][s] = *(const short8*)(wT + col*128 + s*32 + lk*8);
  }
  f32x4 acc[8][2];
  #pragma unroll
  for(int m=0;m<8;m++){ acc[m][0] = (f32x4)0.f; acc[m][1] = (f32x4)0.f; }
  #pragma unroll
  for(int m=0; m<8; m++){
    const ushort* ap = lds_a + (m*16 + lc)*136 + lk*8;
    #pragma unroll
    for(int s=0; s<4; s++){
      short8 a = *(const short8*)(ap + s*32);
      acc[m][0] = __builtin_amdgcn_mfma_f32_16x16x32_bf16(a, bfrag[0][s], acc[m][0], 0, 0, 0);
      acc[m][1] = __builtin_amdgcn_mfma_f32_16x16x32_bf16(a, bfrag[1][s], acc[m][1], 0, 0, 0);
    }
  }
  __syncthreads();     // MFMA reads of lds_a done; reuse as C staging tile

  #pragma unroll
  for(int m=0; m<8; m++){
    #pragma unroll
    for(int tt=0; tt<2; tt++){
      int colg = wv*32 + tt*16 + lc;
      #pragma unroll
      for(int r=0; r<4; r++){
        int row = m*16 + lk*4 + r;
        lds_a[row*136 + colg] = f2b(acc[m][tt][r] * sdinv[row]);
      }
    }
  }
  __syncthreads();
  {
    ushort* gout = g + (size_t)row0*128;
    int maxrow = NN - row0; if(maxrow > 128) maxrow = 128;
    #pragma unroll
    for(int i=0; i<8; i++){
      int idx = i*256 + t;
      int row = idx >> 4, grp = idx & 15;
      if(row < maxrow){
        short8 c8 = *(const short8*)(lds_a + row*136 + grp*8);
        *(short8*)(gout + row*128 + grp*8) = c8;
      }
    }
  }
}

// ---------------- aggregation v2: 16 lanes/node, ushort8 gathers, 32-bit addressing --------
// out[n] = bf16( dinv[n]*(sum_{e->n} g[src] + g[n]) + bias )
__global__ __launch_bounds__(256)
void k_agg(const ushort* __restrict__ g, const int* __restrict__ rowstart,
           const int* __restrict__ srcs, const float* __restrict__ dinv,
           const float* __restrict__ bias, ushort* __restrict__ outp)
{
  const int lane = threadIdx.x & 15;          // 16 lanes x 16B = 256B row
  const int node = blockIdx.x*16 + (threadIdx.x >> 4);
  const unsigned loff = (unsigned)lane << 4;  // byte offset within row (loop-invariant)
  const char* gbase = (const char*)g;
  const int e0 = rowstart[node], e1 = rowstart[node+1];
  float acc0[8], acc1[8];
  #pragma unroll
  for(int k=0;k<8;k++){ acc0[k]=0.f; acc1[k]=0.f; }
  int e = e0;
  for(; e+7 < e1; e += 8){                    // 8 outstanding 16B gathers
    int si[8];
    #pragma unroll
    for(int i=0;i<8;i++) si[i] = srcs[e+i];
    short8 v[8];
    #pragma unroll
    for(int i=0;i<8;i++) v[i] = *(const short8*)(gbase + (((unsigned)si[i]<<8) + loff));
    #pragma unroll
    for(int i=0;i<8;i++){
      #pragma unroll
      for(int k=0;k<8;k++){
        float f = b2f((ushort)v[i][k]);
        if(i&1) acc1[k] += f; else acc0[k] += f;
      }
    }
  }
  for(; e+3 < e1; e += 4){
    int si[4];
    #pragma unroll
    for(int i=0;i<4;i++) si[i] = srcs[e+i];
    short8 v[4];
    #pragma unroll
    for(int i=0;i<4;i++) v[i] = *(const short8*)(gbase + (((unsigned)si[i]<<8) + loff));
    #pragma unroll
    for(int i=0;i<4;i++){
      #pragma unroll
      for(int k=0;k<8;k++){
        float f = b2f((ushort)v[i][k]);
        if(i&1) acc1[k] += f; else acc0[k] += f;
      }
    }
  }
  for(; e < e1; e++){
    short8 v = *(const short8*)(gbase + (((unsigned)srcs[e]<<8) + loff));
    #pragma unroll
    for(int k=0;k<8;k++) acc0[k] += b2f((ushort)v[k]);
  }
  short8 vs = *(const short8*)(gbase + (((unsigned)node<<8) + loff));
  float dv = dinv[node];
  short8 o8;
  #pragma unroll
  for(int k=0;k<8;k++){
    float bv = bias[lane*8 + k];
    o8[k] = (short)f2b(dv*(acc0[k] + acc1[k] + b2f((ushort)vs[k])) + bv);
  }
  *(short8*)((char*)outp + (((unsigned)node<<8) + loff)) = o8;
}

// ---------------- per-graph moments, vectorized: ushort8 loads, 8 rows/iter ----------------
__global__ __launch_bounds__(128)
void k_stats(const ushort* __restrict__ x, const int* __restrict__ gstart,
             float* __restrict__ S1, float* __restrict__ S2)
{
  __shared__ float sb1[128][9], sb2[128][9];   // +1 pad: conflict-free
  int g = blockIdx.x, ch = blockIdx.y, t = threadIdx.x;
  int grp = t & 15, ro = t >> 4;
  int s = gstart[g], e = gstart[g+1];
  int len = e - s;
  int i0 = s + (int)((long long)len * ch / STAT_CH);
  int i1 = s + (int)((long long)len * (ch+1) / STAT_CH);
  float a1[8], a2[8];
  #pragma unroll
  for(int k=0;k<8;k++){ a1[k]=0.f; a2[k]=0.f; }
  for(int n = i0 + ro; n < i1; n += 8){
    short8 v8 = *(const short8*)(x + (size_t)n*128 + grp*8);
    #pragma unroll
    for(int k=0;k<8;k++){
      float v = b2f((ushort)v8[k]);
      a1[k] += v; a2[k] += v*v;
    }
  }
  #pragma unroll
  for(int k=0;k<8;k++){ sb1[t][k]=a1[k]; sb2[t][k]=a2[k]; }
  __syncthreads();
  if(ro < 4){
    #pragma unroll
    for(int k=0;k<8;k++){ sb1[t][k]+=sb1[t+64][k]; sb2[t][k]+=sb2[t+64][k]; }
  }
  __syncthreads();
  if(ro < 2){
    #pragma unroll
    for(int k=0;k<8;k++){ sb1[t][k]+=sb1[t+32][k]; sb2[t][k]+=sb2[t+32][k]; }
  }
  __syncthreads();
  if(ro < 1){
    #pragma unroll
    for(int k=0;k<8;k++){ sb1[t][k]+=sb1[t+16][k]; sb2[t][k]+=sb2[t+16][k]; }
  }
  __syncthreads();
  if(t < 16 && i1 > i0){
    #pragma unroll
    for(int k=0;k<8;k++){
      atomicAdd(&S1[g*128 + t*8 + k], sb1[t][k]);
      atomicAdd(&S2[g*128 + t*8 + k], sb2[t][k]);
    }
  }
}

// ---------------- pool, vectorized: relu(norm(x)) summed; norm inline from S1/S2 -----------
__global__ __launch_bounds__(128)
void k_pool(const ushort* __restrict__ x, const int* __restrict__ gstart,
            const float* __restrict__ gw, const float* __restrict__ gb,
            const float* __restrict__ ga, const float* __restrict__ S1,
            const float* __restrict__ S2, float* __restrict__ pooled)
{
  __shared__ float sb[128][9];
  int g = blockIdx.x, ch = blockIdx.y, t = threadIdx.x;
  int grp = t & 15, ro = t >> 4;
  int s = gstart[g], e = gstart[g+1];
  int len = e - s;
  int i0 = s + (int)((long long)len * ch / POOL_CH);
  int i1 = s + (int)((long long)len * (ch+1) / POOL_CH);
  float inv = 1.f/(float)(len > 0 ? len : 1);
  float am[8], rs[8], wv[8], bv[8];
  #pragma unroll
  for(int k=0;k<8;k++){
    int f = grp*8 + k;
    float a = ga[f];
    float m = S1[g*128+f]*inv, ex2 = S2[g*128+f]*inv;
    am[k] = a*m;
    rs[k] = rsqrtf(ex2 - (2.f*a - a*a)*m*m + EPSV);
    wv[k] = gw[f]; bv[k] = gb[f];
  }
  float acc[8];
  #pragma unroll
  for(int k=0;k<8;k++) acc[k] = 0.f;
  for(int n = i0 + ro; n < i1; n += 8){
    short8 v8 = *(const short8*)(x + (size_t)n*128 + grp*8);
    #pragma unroll
    for(int k=0;k<8;k++){
      float v = wv[k]*(b2f((ushort)v8[k]) - am[k])*rs[k] + bv[k];
      acc[k] += fmaxf(v, 0.f);
    }
  }
  #pragma unroll
  for(int k=0;k<8;k++) sb[t][k] = acc[k];
  __syncthreads();
  if(ro < 4){
    #pragma unroll
    for(int k=0;k<8;k++) sb[t][k] += sb[t+64][k];
  }
  __syncthreads();
  if(ro < 2){
    #pragma unroll
    for(int k=0;k<8;k++) sb[t][k] += sb[t+32][k];
  }
  __syncthreads();
  if(ro < 1){
    #pragma unroll
    for(int k=0;k<8;k++) sb[t][k] += sb[t+16][k];
  }
  __syncthreads();
  if(t < 16 && i1 > i0){
    #pragma unroll
    for(int k=0;k<8;k++)
      atomicAdd(&pooled[g*128 + t*8 + k], sb[t][k]);
  }
}

// ---------------- head: logits = pooled/cnt @ lw + lb, log_softmax ----------------
__global__ __launch_bounds__(64)
void k_head(const float* __restrict__ pooled, const int* __restrict__ gstart,
            const float* __restrict__ lw, const float* __restrict__ lb,
            float* __restrict__ out)
{
  int g = blockIdx.x, t = threadIdx.x;
  __shared__ float lg[NC];
  __shared__ float lse_s;
  int len = gstart[g+1] - gstart[g];
  float inv = 1.f/(float)(len > 0 ? len : 1);
  if(t < NC){
    float acc = lb[t];
    for(int f=0; f<128; f++) acc += pooled[g*128+f]*inv*lw[f*NC + t];
    lg[t] = acc;
  }
  __syncthreads();
  if(t == 0){
    float mx = -1e30f;
    for(int c=0;c<NC;c++) mx = fmaxf(mx, lg[c]);
    float sm = 0.f;
    for(int c=0;c<NC;c++) sm += expf(lg[c]-mx);
    lse_s = mx + logf(sm);
  }
  __syncthreads();
  if(t < NC) out[g*NC + t] = lg[t] - lse_s;
}

// ---------------- launch (14 dispatches) ----------------
extern "C" void kernel_launch(void* const* d_in, const int* in_sizes, int n_in,
                              void* d_out, int out_size, void* d_ws, size_t ws_size,
                              hipStream_t stream)
{
  const float* x    = (const float*)d_in[0];
  const int*   ei   = (const int*)d_in[1];
  const int*   batch= (const int*)d_in[2];
  const float* w1   = (const float*)d_in[3];
  const float* b1   = (const float*)d_in[4];
  const float* w2   = (const float*)d_in[5];
  const float* b2   = (const float*)d_in[6];
  const float* w3   = (const float*)d_in[7];
  const float* b3   = (const float*)d_in[8];
  const float* g1w  = (const float*)d_in[9];
  const float* g1b  = (const float*)d_in[10];
  const float* g1a  = (const float*)d_in[11];
  const float* g2w  = (const float*)d_in[12];
  const float* g2b  = (const float*)d_in[13];
  const float* g2a  = (const float*)d_in[14];
  const float* g3w  = (const float*)d_in[15];
  const float* g3b  = (const float*)d_in[16];
  const float* g3a  = (const float*)d_in[17];
  const float* lw   = (const float*)d_in[18];
  const float* lb   = (const float*)d_in[19];
  float* out = (float*)d_out;

  char* p = (char*)d_ws;
  auto take = [&](size_t nbytes){ char* q = p; p += (nbytes + 255) & ~(size_t)255; return q; };
  ushort* gbuf    = (ushort*)take((size_t)NN*HD*2);
  ushort* bufB    = (ushort*)take((size_t)NN*HD*2);
  ushort* wT      = (ushort*)take((size_t)3*HD*HD*2);
  unsigned* ebuf  = (unsigned*)take((size_t)NBKT*BCAP*4);
  int*   srcs     = (int*)  take((size_t)NE*4);
  int*   rowstart = (int*)  take((size_t)(NN+1)*4);
  float* dinv     = (float*)take((size_t)NN*4);
  int*   cursor0  = (int*)  take((size_t)NBKT*4);
  int*   gstart   = (int*)  take((size_t)(NG+1)*4);
  float* Sbase    = (float*)take((size_t)(3*2*NG*HD + NG*HD)*4);  // 3x(S1,S2) + pooled
  if((size_t)(p - (char*)d_ws) > ws_size) return;  // workspace too small: fail visibly

  float* SL1  = Sbase;
  float* SL1b = Sbase + 1*NG*HD;
  float* SL2  = Sbase + 2*NG*HD;
  float* SL2b = Sbase + 3*NG*HD;
  float* SL3  = Sbase + 4*NG*HD;
  float* SL3b = Sbase + 5*NG*HD;
  float* pooled = Sbase + 6*NG*HD;

  k_init <<<409, 256, 0, stream>>>(batch, gstart, w1, w2, w3, wT, cursor0, rowstart, Sbase);
  k_bin  <<<BIN_BLOCKS, 256, 0, stream>>>(ei, cursor0, ebuf);
  k_sort <<<NBKT, 256, 0, stream>>>(ebuf, cursor0, srcs, rowstart, dinv);

  const int GB = (NN + 127)/128;     // 782
  const int AB = (NN + 15)/16;       // 6250

  // ---- layer 1 ----
  k_gemm<0><<<GB, 256, 0, stream>>>(x, wT, gbuf, dinv, batch,
                                    nullptr, nullptr, nullptr, nullptr, nullptr, gstart);
  k_agg<<<AB, 256, 0, stream>>>(gbuf, rowstart, srcs, dinv, b1, bufB);
  k_stats<<<dim3(NG, STAT_CH), 128, 0, stream>>>(bufB, gstart, SL1, SL1b);

  // ---- layer 2 ----
  k_gemm<1><<<GB, 256, 0, stream>>>(bufB, wT + 16384, gbuf, dinv, batch,
                                    g1w, g1b, g1a, SL1, SL1b, gstart);
  k_agg<<<AB, 256, 0, stream>>>(gbuf, rowstart, srcs, dinv, b2, bufB);
  k_stats<<<dim3(NG, STAT_CH), 128, 0, stream>>>(bufB, gstart, SL2, SL2b);

  // ---- layer 3 ----
  k_gemm<1><<<GB, 256, 0, stream>>>(bufB, wT + 32768, gbuf, dinv, batch,
                                    g2w, g2b, g2a, SL2, SL2b, gstart);
  k_agg<<<AB, 256, 0, stream>>>(gbuf, rowstart, srcs, dinv, b3, bufB);
  k_stats<<<dim3(NG, STAT_CH), 128, 0, stream>>>(bufB, gstart, SL3, SL3b);

  // ---- pool + head ----
  k_pool<<<dim3(NG, POOL_CH), 128, 0, stream>>>(bufB, gstart, g3w, g3b, g3a, SL3, SL3b, pooled);
  k_head<<<NG, 64, 0, stream>>>(pooled, gstart, lw, lb, out);
}